// Round 10
// baseline (692.923 us; speedup 1.0000x reference)
//
#include <hip/hip_runtime.h>
#include <math.h>

#define B_      4
#define C_      32
#define COND_   80
#define LMEL_   2048
#define HOP_    8
#define UP_     8
#define LAYERS_ 4
#define K_      3
#define HID_    64
#define KPK_    3
#define EMB_    512
#define LAUD_   (LMEL_*UP_)          // 16384
#define KCH_    (LAYERS_*C_*2*C_*K_) // 24576
#define BCH_    (LAYERS_*2*C_)       // 256
#define Y2S     (LAUD_ + 8)          // padded y2 row stride (+4 each side)

typedef short v8s __attribute__((ext_vector_type(8)));
typedef float v4f __attribute__((ext_vector_type(4)));

__device__ __forceinline__ float lrelu_(float v, float s) { return v >= 0.f ? v : s * v; }

__device__ __forceinline__ unsigned short f2bf(float f) {  // RNE float->bf16
  unsigned int x = __float_as_uint(f);
  unsigned int r = (x + 0x7FFFu + ((x >> 16) & 1u)) >> 16;
  return (unsigned short)r;
}

// ---------------------------------------------------------------- prep: generic slab transpose src[s][oc][ick] -> dst[s][ick][oc]
__global__ void k_mkWTs(const float* __restrict__ src, float* __restrict__ dst,
                        int S, int OC, int ICK) {
  int idx = blockIdx.x*256 + threadIdx.x;
  if (idx >= S*OC*ICK) return;
  int s = idx / (OC*ICK), rem = idx % (OC*ICK);
  int oc = rem / ICK, ick = rem % ICK;
  dst[s*OC*ICK + ick*OC + oc] = src[idx];
}

// ---------------------------------------------------------------- K1: noise + condition
__global__ void k_noise_cond(const float* __restrict__ ne, const float* __restrict__ fw,
                             const float* __restrict__ fb, const float* __restrict__ c,
                             float* __restrict__ cond) {
  int b = blockIdx.x / COND_;
  int cc = blockIdx.x % COND_;
  __shared__ float red[256];
  float p = 0.f;
  for (int j = threadIdx.x; j < EMB_; j += 256)
    p += ne[b*EMB_ + j] * fw[cc*EMB_ + j];
  red[threadIdx.x] = p;
  __syncthreads();
  for (int s = 128; s > 0; s >>= 1) {
    if (threadIdx.x < s) red[threadIdx.x] += red[threadIdx.x + s];
    __syncthreads();
  }
  float noise = red[0] + fb[cc];
  const float* cp = c + (b*COND_ + cc)*LMEL_;
  float* op = cond + (b*COND_ + cc)*LMEL_;
  for (int l = threadIdx.x; l < LMEL_; l += 256) op[l] = cp[l] + noise;
}

// ---------------------------------------------------------------- K2: KP input conv (80->64, k=5, pad=2, lrelu 0.1), T=32, wT[(cc*5+k)*64+ch]
__global__ __launch_bounds__(256) void k_kp_in(const float* __restrict__ cond, const float* __restrict__ wT,
                                               const float* __restrict__ bias, float* __restrict__ out) {
  const int T = 32;
  int b  = blockIdx.x / (LMEL_/T);
  int lb = (blockIdx.x % (LMEL_/T)) * T;
  __shared__ float sc[COND_][T + 4];
  for (int idx = threadIdx.x; idx < COND_*(T+4); idx += 256) {
    int cc = idx / (T+4), j = idx % (T+4);
    int l = lb + j - 2;
    sc[cc][j] = (l >= 0 && l < LMEL_) ? cond[(b*COND_ + cc)*LMEL_ + l] : 0.f;
  }
  __syncthreads();
  int ch = threadIdx.x & 63;
  int lq = threadIdx.x >> 6;  // 0..3, 8 l's each
  float acc[8];
#pragma unroll
  for (int ii = 0; ii < 8; ii++) acc[ii] = bias[ch];
  for (int cc = 0; cc < COND_; cc++) {
    float r[12];
#pragma unroll
    for (int j = 0; j < 12; j++) r[j] = sc[cc][lq*8 + j];
#pragma unroll
    for (int k = 0; k < 5; k++) {
      float wv = wT[(cc*5 + k)*64 + ch];
#pragma unroll
      for (int ii = 0; ii < 8; ii++) acc[ii] = fmaf(wv, r[ii + k], acc[ii]);
    }
  }
  float* op = out + (b*HID_ + ch)*LMEL_ + lb + lq*8;
#pragma unroll
  for (int ii = 0; ii < 8; ii++) acc[ii] = lrelu_(acc[ii], 0.1f);
  *reinterpret_cast<float4*>(&op[0]) = make_float4(acc[0], acc[1], acc[2], acc[3]);
  *reinterpret_cast<float4*>(&op[4]) = make_float4(acc[4], acc[5], acc[6], acc[7]);
}

// ---------------------------------------------------------------- K3: fused res pair: out = in + lrelu(conv2(lrelu(conv1(in))))
__global__ __launch_bounds__(256) void k_kp_res2(const float* __restrict__ in,
                                                 const float* __restrict__ w1T, const float* __restrict__ b1,
                                                 const float* __restrict__ w2T, const float* __restrict__ b2,
                                                 float* __restrict__ out) {
  const int T = 32;
  int b  = blockIdx.x / (LMEL_/T);
  int lb = (blockIdx.x % (LMEL_/T)) * T;
  __shared__ float si[HID_][38];   // cols lb-2 .. lb+33 (36 used)
  __shared__ float sr[HID_][38];   // intermediate r, cols lb-1 .. lb+32 (34 used)
  for (int idx = threadIdx.x; idx < HID_*36; idx += 256) {
    int cc = idx / 36, j = idx % 36;
    int l = lb - 2 + j;
    si[cc][j] = (l >= 0 && l < LMEL_) ? in[(b*HID_ + cc)*LMEL_ + l] : 0.f;
  }
  __syncthreads();
  int ch = threadIdx.x & 63;
  int lq = threadIdx.x >> 6;   // 0..3
  {
    float b1v = b1[ch];
    float a1[9];
#pragma unroll
    for (int jj = 0; jj < 9; jj++) a1[jj] = b1v;
    for (int cc = 0; cc < HID_; cc++) {
      float r[11];
#pragma unroll
      for (int j = 0; j < 11; j++) r[j] = si[cc][lq*9 + j];
#pragma unroll
      for (int k = 0; k < 3; k++) {
        float wv = w1T[(cc*3 + k)*64 + ch];
#pragma unroll
        for (int jj = 0; jj < 9; jj++) a1[jj] = fmaf(wv, r[jj + k], a1[jj]);
      }
    }
#pragma unroll
    for (int jj = 0; jj < 9; jj++) {
      int m = lq*9 + jj;
      if (m < 34) sr[ch][m] = lrelu_(a1[jj], 0.1f);
    }
  }
  __syncthreads();
  {
    float b2v = b2[ch];
    float a2[8];
#pragma unroll
    for (int jj = 0; jj < 8; jj++) a2[jj] = b2v;
    for (int cc = 0; cc < HID_; cc++) {
      float r[10];
#pragma unroll
      for (int j = 0; j < 10; j++) r[j] = sr[cc][lq*8 + j];
#pragma unroll
      for (int k = 0; k < 3; k++) {
        float wv = w2T[(cc*3 + k)*64 + ch];
#pragma unroll
        for (int jj = 0; jj < 8; jj++) a2[jj] = fmaf(wv, r[jj + k], a2[jj]);
      }
    }
    float* op = out + (b*HID_ + ch)*LMEL_ + lb + lq*8;
    float v[8];
#pragma unroll
    for (int jj = 0; jj < 8; jj++)
      v[jj] = si[ch][lq*8 + jj + 2] + lrelu_(a2[jj], 0.1f);
    *reinterpret_cast<float4*>(&op[0]) = make_float4(v[0], v[1], v[2], v[3]);
    *reinterpret_cast<float4*>(&op[4]) = make_float4(v[4], v[5], v[6], v[7]);
  }
}

// ---------------------------------------------------------------- K4: bias conv (64->256, k=3, pad=1), T=16, wT[(cc*3+k)*256+ch]
__global__ __launch_bounds__(256) void k_kp_bias(const float* __restrict__ in, const float* __restrict__ wT,
                                                 const float* __restrict__ bias, float* __restrict__ out) {
  const int T = 16;
  int b  = blockIdx.x / (LMEL_/T);
  int lb = (blockIdx.x % (LMEL_/T)) * T;
  __shared__ float si[HID_][T + 2];
  for (int idx = threadIdx.x; idx < HID_*(T+2); idx += 256) {
    int cc = idx / (T+2), j = idx % (T+2);
    int l = lb + j - 1;
    si[cc][j] = (l >= 0 && l < LMEL_) ? in[(b*HID_ + cc)*LMEL_ + l] : 0.f;
  }
  __syncthreads();
  int ch = threadIdx.x;  // 0..255
  float acc[T];
  float bv = bias[ch];
#pragma unroll
  for (int ii = 0; ii < T; ii++) acc[ii] = bv;
  for (int cc = 0; cc < HID_; cc++) {
    float w0 = wT[(cc*3 + 0)*256 + ch];
    float w1 = wT[(cc*3 + 1)*256 + ch];
    float w2 = wT[(cc*3 + 2)*256 + ch];
#pragma unroll
    for (int ii = 0; ii < T; ii++)
      acc[ii] = fmaf(w0, si[cc][ii], fmaf(w1, si[cc][ii+1], fmaf(w2, si[cc][ii+2], acc[ii])));
  }
  float* op = out + (b*BCH_ + ch)*LMEL_ + lb;
#pragma unroll
  for (int q = 0; q < 4; q++)
    *reinterpret_cast<float4*>(&op[q*4]) = make_float4(acc[q*4], acc[q*4+1], acc[q*4+2], acc[q*4+3]);
}

// ---------------------------------------------------------------- prep: upsample weight transpose -> wt[(ci*16+j)*32+co]
__global__ void k_mkUp(const float* __restrict__ upw, float* __restrict__ wt) {
  int idx = blockIdx.x*256 + threadIdx.x;
  if (idx >= C_*C_*16) return;
  int co = idx & 31, j = (idx >> 5) & 15, ci = idx >> 9;
  wt[idx] = upw[(ci*C_ + co)*16 + j];
}

// ---------------------------------------------------------------- K5: upsample (conv_transpose1d stride 8, k=16, pad=4), lrelu(x,0.2) input
#define UT 32
__global__ __launch_bounds__(256) void k_upsample(const float* __restrict__ x, const float* __restrict__ wt,
                                                  float* __restrict__ h) {
  int b  = blockIdx.x / 65;
  int s0 = (blockIdx.x % 65) * UT;
  __shared__ float sw[16384];          // [ci][j][co]
  __shared__ float sx[C_][33 + 3];
  for (int idx = threadIdx.x*4; idx < 16384; idx += 1024)
    *reinterpret_cast<float4*>(&sw[idx]) = *reinterpret_cast<const float4*>(&wt[idx]);
  for (int idx = threadIdx.x; idx < C_*33; idx += 256) {
    int ci = idx / 33, i = idx % 33;
    int s = s0 - 1 + i;
    float v = (s >= 0 && s < LMEL_) ? x[(b*C_ + ci)*LMEL_ + s] : 0.f;
    sx[ci][i] = lrelu_(v, 0.2f);
  }
  __syncthreads();
  int co = threadIdx.x & 31, sq = threadIdx.x >> 5;  // sq 0..7, 4 frames each
  float acc[4][8];
#pragma unroll
  for (int k = 0; k < 4; k++)
#pragma unroll
    for (int r = 0; r < 8; r++) acc[k][r] = 0.f;
  for (int ci = 0; ci < C_; ci++) {
    float xv[5];
#pragma unroll
    for (int m = 0; m < 5; m++) xv[m] = sx[ci][sq*4 + m];
    const float* wl = &sw[ci*512 + co];
#pragma unroll
    for (int r = 0; r < 8; r++) {
      float wa = wl[r*32];
      float wb = wl[(r+8)*32];
#pragma unroll
      for (int k = 0; k < 4; k++)
        acc[k][r] = fmaf(wa, sx[ci][sq*4 + k + 1], fmaf(wb, xv[k], acc[k][r]));
    }
  }
  float* op = h + ((size_t)b*C_ + co)*LAUD_;
#pragma unroll
  for (int k = 0; k < 4; k++) {
    int s1 = s0 + sq*4 + k;
    int lo = 8*s1 - 4;
    if (lo >= 0 && lo + 4 <= LAUD_)
      *reinterpret_cast<float4*>(&op[lo]) = make_float4(acc[k][0], acc[k][1], acc[k][2], acc[k][3]);
    if (lo >= -4 && lo + 8 <= LAUD_)
      *reinterpret_cast<float4*>(&op[lo+4]) = make_float4(acc[k][4], acc[k][5], acc[k][6], acc[k][7]);
  }
}

// ---------------------------------------------------------------- prep: A-fragment-ordered bf16 weights
__global__ void k_mkA(const float* __restrict__ kw, unsigned short* __restrict__ waf) {
  int idx = blockIdx.x*256 + threadIdx.x;
  if (idx >= KCH_*HID_*KPK_) return;   // 4,718,592
  int i    = idx & 7;
  int lane = (idx >> 3) & 63;
  int ks   = (idx >> 9) % 6;
  int tile = (idx / 3072) & 3;
  int rk   = idx / 12288;              // 0..383
  int layer = rk / 96, rem = rk % 96, ci = rem / 3, kk = rem % 3;
  int cout = tile*16 + (lane & 15);
  int j    = ks*32 + ((lane >> 4) << 3) + i;
  int row  = ((layer*32 + ci)*64 + cout)*3 + kk;
  waf[idx] = f2bf(kw[row*192 + j]);
}

// ---------------------------------------------------------------- prep: kernel-conv bias reordered
__global__ void k_mkKbT(const float* __restrict__ kb, float* __restrict__ kbt) {
  int idx = blockIdx.x*256 + threadIdx.x;
  if (idx >= KCH_) return;             // 24576
  int cr = idx & 15, tile = (idx >> 4) & 3, rk = idx >> 6;
  int layer = rk / 96, rem = rk % 96, ci = rem / 3, kk = rem % 3;
  int cout = tile*16 + cr;
  kbt[idx] = kb[((layer*32 + ci)*64 + cout)*3 + kk];
}

// ---------------------------------------------------------------- K6: dilated conv (32->32, k=3) on lrelu(h+ad,0.2), out lrelu 0.2, T=128
// Writes into PADDED y2 buffer (row stride Y2S, data at +4); edge blocks zero the pads.
template<int DIL>
__global__ __launch_bounds__(256) void k_dilconv(const float* __restrict__ h, const float* __restrict__ ad,
                                                 const float* __restrict__ wT, float* __restrict__ y2p) {
  const int T = 128;
  int b  = blockIdx.x / (LAUD_/T);
  int tb = (blockIdx.x % (LAUD_/T)) * T;
  const int W = T + 2*DIL;
  __shared__ float ss[C_][T + 2*27 + 4];
  for (int idx = threadIdx.x; idx < C_*W; idx += 256) {
    int ci = idx / W, j = idx % W;
    int t = tb - DIL + j;
    float v = 0.f;
    if (t >= 0 && t < LAUD_) {
      int g = (b*C_ + ci)*LAUD_ + t;
      v = h[g] + ad[g];
    }
    ss[ci][j] = lrelu_(v, 0.2f);
  }
  // zero y2 pads (left pad at row*Y2S+0..3, right pad at row*Y2S+4+LAUD..+3)
  if (tb == 0 && threadIdx.x < 128) {
    int ci = threadIdx.x >> 2, q = threadIdx.x & 3;
    y2p[(size_t)(b*C_ + ci)*Y2S + q] = 0.f;
  }
  if (tb == LAUD_ - T && threadIdx.x < 128) {
    int ci = threadIdx.x >> 2, q = threadIdx.x & 3;
    y2p[(size_t)(b*C_ + ci)*Y2S + 4 + LAUD_ + q] = 0.f;
  }
  __syncthreads();
  int co = threadIdx.x & 31, tq = threadIdx.x >> 5;
  float acc[16];
#pragma unroll
  for (int ii = 0; ii < 16; ii++) acc[ii] = 0.f;
  for (int ci = 0; ci < C_; ci++) {
    float w0 = wT[(ci*3 + 0)*32 + co];
    float w1 = wT[(ci*3 + 1)*32 + co];
    float w2 = wT[(ci*3 + 2)*32 + co];
#pragma unroll
    for (int ii = 0; ii < 16; ii++) {
      int tl = tq*16 + ii;
      acc[ii] = fmaf(w0, ss[ci][tl], fmaf(w1, ss[ci][tl + DIL], fmaf(w2, ss[ci][tl + 2*DIL], acc[ii])));
    }
  }
  float* op = y2p + (size_t)(b*C_ + co)*Y2S + 4 + tb + tq*16;
#pragma unroll
  for (int ii = 0; ii < 16; ii++) acc[ii] = lrelu_(acc[ii], 0.2f);
#pragma unroll
  for (int q = 0; q < 4; q++)
    *reinterpret_cast<float4*>(&op[q*4]) = make_float4(acc[q*4], acc[q*4+1], acc[q*4+2], acc[q*4+3]);
}

// ---------------------------------------------------------------- K7: MFMA-fused KP-GEMM + LVC + gate + h update
// 512 thr, 8 waves = wq(0..3 ci-quarters) x tp(0..1). Block owns tiles {variant, variant+2}.
// y2 read DIRECT from padded global (no LDS stage); shh aliases red (barrier-separated).
// LDS = red 16896 + FB 12288 = 29184 B -> 2+ blocks/CU by every resource.
// launch_bounds min-waves stays 2 ((512,4) forces 64-reg arch split -> spill, r5/r6).
#define FR2 32
#define RED(t, l, rs) red[(((t)*64 + (l))*33) + (rs)]

#define LOADY(SYR, TBASE)                                                        \
  {                                                                              \
    const float* yp = yr + (TBASE);                                              \
    float4 qa = *reinterpret_cast<const float4*>(yp - 4);                        \
    float4 qb = *reinterpret_cast<const float4*>(yp);                            \
    float4 qc = *reinterpret_cast<const float4*>(yp + 4);                        \
    float4 qd = *reinterpret_cast<const float4*>(yp + 8);                        \
    SYR[0] = qa.w;                                                               \
    SYR[1] = qb.x; SYR[2] = qb.y; SYR[3] = qb.z; SYR[4] = qb.w;                  \
    SYR[5] = qc.x; SYR[6] = qc.y; SYR[7] = qc.z; SYR[8] = qc.w;                  \
    SYR[9] = qd.x; SYR[10] = qd.y; SYR[11] = qd.z;                               \
  }

#define EPILOGUE(G, OO)                                                          \
  {                                                                              \
    __syncthreads();                                                             \
    if (wq == 3) {                                                               \
      _Pragma("unroll") for (int r = 0; r < 4; r++)                              \
        _Pragma("unroll") for (int s = 0; s < 8; s++)                            \
          RED(tp, lane, r*8 + s) = OO[r][s];                                     \
    }                                                                            \
    __syncthreads();                                                             \
    if (wq == 2) {                                                               \
      _Pragma("unroll") for (int r = 0; r < 4; r++)                              \
        _Pragma("unroll") for (int s = 0; s < 8; s++)                            \
          RED(tp, lane, r*8 + s) += OO[r][s];                                    \
    }                                                                            \
    __syncthreads();                                                             \
    if (wq == 1) {                                                               \
      _Pragma("unroll") for (int r = 0; r < 4; r++)                              \
        _Pragma("unroll") for (int s = 0; s < 8; s++)                            \
          RED(tp, lane, r*8 + s) += OO[r][s];                                    \
    }                                                                            \
    __syncthreads();                                                             \
    if (wq == 0) {                                                               \
      _Pragma("unroll") for (int r = 0; r < 4; r++) {                            \
        int cout = tile*16 + ((lane >> 4) << 2) + r;                             \
        float bv = biasb[((size_t)b*BCH_ + layer*2*C_ + cout)*LMEL_ + l0 + G*16 + f]; \
        _Pragma("unroll") for (int s = 0; s < 8; s++)                            \
          OO[r][s] += RED(tp, lane, r*8 + s) + bv;                               \
      }                                                                          \
      if (tp == 1) {                                                             \
        _Pragma("unroll") for (int r = 0; r < 4; r++)                            \
          _Pragma("unroll") for (int s = 0; s < 8; s++)                          \
            RED(1, lane, r*8 + s) = OO[r][s];                                    \
      }                                                                          \
    }                                                                            \
    __syncthreads();                                                             \
    if (wq == 0 && tp == 0) {                                                    \
      _Pragma("unroll") for (int r = 0; r < 4; r++) {                            \
        int cout = tile*16 + ((lane >> 4) << 2) + r;                             \
        size_t base = ((size_t)b*C_ + cout)*LAUD_ + (size_t)(l0 + G*16 + f)*HOP_;\
        float4 h0 = *reinterpret_cast<const float4*>(&h[base]);                  \
        float4 h1 = *reinterpret_cast<const float4*>(&h[base + 4]);              \
        float4 a0 = *reinterpret_cast<const float4*>(&ad[base]);                 \
        float4 a1 = *reinterpret_cast<const float4*>(&ad[base + 4]);             \
        float outv[8];                                                           \
        _Pragma("unroll") for (int s = 0; s < 8; s++) {                          \
          float v  = OO[r][s];                                                   \
          float tv = RED(1, lane, r*8 + s);                                      \
          float sig = 1.f / (1.f + __expf(-v));                                  \
          float th  = 1.f - 2.f / (1.f + __expf(2.f*tv));                        \
          float hv = (s < 4) ? ((const float*)&h0)[s] : ((const float*)&h1)[s-4];\
          float av = (s < 4) ? ((const float*)&a0)[s] : ((const float*)&a1)[s-4];\
          outv[s] = hv + av + sig * th;                                          \
        }                                                                        \
        *reinterpret_cast<float4*>(&h[base])     = make_float4(outv[0], outv[1], outv[2], outv[3]); \
        *reinterpret_cast<float4*>(&h[base + 4]) = make_float4(outv[4], outv[5], outv[6], outv[7]); \
      }                                                                          \
    }                                                                            \
  }

__global__ __launch_bounds__(512, 2) void k_lvc_mfma(
    const float* __restrict__ hkp, const unsigned short* __restrict__ waf,
    const float* __restrict__ kbt, const float* __restrict__ biasb,
    const float* __restrict__ y2p, const float* __restrict__ ad,
    float* __restrict__ h, int layer) {
  int b  = blockIdx.x >> 7;               // 64 frame-tiles x 2 variants
  int r7 = blockIdx.x & 127;
  int l0 = (r7 >> 1) * FR2;
  int variant = r7 & 1;

  __shared__ __align__(16) float red[2*64*33];            // 16896 B; shh aliases front
  __shared__ __align__(16) unsigned short FB[2*6*64*8];   // 12288 B
  float* shh = red;                                       // [HID_][34], 8704 B, dead after FB build

  int tid = threadIdx.x;
  for (int idx = tid; idx < HID_*34; idx += 512) {
    int hh = idx / 34, j = idx % 34;
    int l = l0 - 1 + j;
    shh[hh*34 + j] = (l >= 0 && l < LMEL_) ? hkp[(b*HID_ + hh)*LMEL_ + l] : 0.f;
  }
  __syncthreads();
  for (int idx = tid; idx < 6144; idx += 512) {
    int i = idx & 7, lane2 = (idx >> 3) & 63, gk = idx >> 9;  // gk = g*6+ks
    int ks = gk % 6, g = gk / 6;
    int k = ks*32 + ((lane2 >> 4) << 3) + i;
    int col = lane2 & 15;
    int hh = k / 3, q = k - hh*3;
    FB[idx] = f2bf(shh[hh*34 + g*16 + col + q]);
  }
  __syncthreads();

  int wave = tid >> 6, lane = tid & 63;
  int tp = wave & 1, wq = wave >> 1;      // tp: tile-pair member, wq: ci-quarter
  int tile = variant + 2*tp;              // {v, v+2}: sigmoid & tanh halves
  int f = lane & 15;

  v8s bfrA[6], bfrB[6];
#pragma unroll
  for (int ks = 0; ks < 6; ks++) {
    bfrA[ks] = *reinterpret_cast<const v8s*>(&FB[(ks*64 + lane)*8]);
    bfrB[ks] = *reinterpret_cast<const v8s*>(&FB[((6 + ks)*64 + lane)*8]);
  }

  float o0[4][8], o1[4][8];
#pragma unroll
  for (int r = 0; r < 4; r++)
#pragma unroll
    for (int s = 0; s < 8; s++) { o0[r][s] = 0.f; o1[r][s] = 0.f; }

  const int rk0 = layer*96 + wq*24;       // 8 ci per quarter = 24 rk
  const unsigned short* wbase = waf + ((size_t)rk0*4 + tile)*3072 + lane*8;
  const float* kbbase = kbt + (rk0*4 + tile)*16 + ((lane >> 4) << 2);
  const float* ybase = y2p + ((size_t)(b*C_ + wq*8))*Y2S + 4;
  const int t0 = (l0 + f)*8;              // g=0 sample base (aligned quad at t0-4)
  const int t1 = (l0 + 16 + f)*8;         // g=1

  for (int ciq = 0; ciq < 8; ciq++) {
    const float* yr = ybase + (size_t)ciq*Y2S;
    float syr0[12], syr1[12];
    LOADY(syr0, t0)
    LOADY(syr1, t1)
#pragma unroll
    for (int kk = 0; kk < 3; kk++) {
      const unsigned short* wp = wbase + (size_t)(ciq*3 + kk)*12288;
      v4f acc0 = {0.f, 0.f, 0.f, 0.f};
      v4f acc1 = {0.f, 0.f, 0.f, 0.f};
#pragma unroll
      for (int ks = 0; ks < 6; ks++) {
        v8s a = *reinterpret_cast<const v8s*>(wp + ks*512);
        acc0 = __builtin_amdgcn_mfma_f32_16x16x32_bf16(a, bfrA[ks], acc0, 0, 0, 0);
        acc1 = __builtin_amdgcn_mfma_f32_16x16x32_bf16(a, bfrB[ks], acc1, 0, 0, 0);
      }
      float4 kb4 = *reinterpret_cast<const float4*>(kbbase + (ciq*3 + kk)*64);
#pragma unroll
      for (int r = 0; r < 4; r++) {
        float k0 = acc0[r] + ((const float*)&kb4)[r];
        float k1 = acc1[r] + ((const float*)&kb4)[r];
#pragma unroll
        for (int s = 0; s < 8; s++) {
          o0[r][s] = fmaf(k0, syr0[kk + s], o0[r][s]);
          o1[r][s] = fmaf(k1, syr1[kk + s], o1[r][s]);
        }
      }
    }
  }

  EPILOGUE(0, o0)
  EPILOGUE(1, o1)
}

// ---------------------------------------------------------------- launcher
extern "C" void kernel_launch(void* const* d_in, const int* in_sizes, int n_in,
                              void* d_out, int out_size, void* d_ws, size_t ws_size,
                              hipStream_t stream) {
  const float* x     = (const float*)d_in[0];
  const float* ad    = (const float*)d_in[1];
  const float* c     = (const float*)d_in[2];
  const float* ne    = (const float*)d_in[3];
  const float* fw    = (const float*)d_in[4];
  const float* fb    = (const float*)d_in[5];
  const float* upw   = (const float*)d_in[6];
  const float* convw = (const float*)d_in[7];
  const float* kinw  = (const float*)d_in[8];
  const float* kinb  = (const float*)d_in[9];
  const float* krw1  = (const float*)d_in[10];
  const float* krb1  = (const float*)d_in[11];
  const float* krw2  = (const float*)d_in[12];
  const float* krb2  = (const float*)d_in[13];
  const float* kkw   = (const float*)d_in[14];
  const float* kkb   = (const float*)d_in[15];
  const float* kbw   = (const float*)d_in[16];
  const float* kbb   = (const float*)d_in[17];
  float* h = (float*)d_out;

  float* ws = (float*)d_ws;
  float* cond   = ws; ws += B_*COND_*LMEL_;
  float* hkpa   = ws; ws += B_*HID_*LMEL_;
  float* hkpb   = ws; ws += B_*HID_*LMEL_;
  float* biasb  = ws; ws += B_*BCH_*LMEL_;
  float* y2p    = ws; ws += B_*C_*Y2S;
  float* kbt    = ws; ws += KCH_;
  float* wtup   = ws; ws += C_*C_*16;
  float* kinwT  = ws; ws += HID_*COND_*5;
  float* krw1T  = ws; ws += 3*HID_*HID_*3;
  float* krw2T  = ws; ws += 3*HID_*HID_*3;
  float* kbwT   = ws; ws += BCH_*HID_*3;
  float* convwT = ws; ws += LAYERS_*C_*C_*3;
  unsigned short* waf = (unsigned short*)ws; ws += (KCH_*HID_*KPK_)/2;

  k_mkA<<<(KCH_*HID_*KPK_ + 255)/256, 256, 0, stream>>>(kkw, waf);
  k_mkKbT<<<(KCH_ + 255)/256, 256, 0, stream>>>(kkb, kbt);
  k_mkUp<<<(C_*C_*16 + 255)/256, 256, 0, stream>>>(upw, wtup);
  k_mkWTs<<<(HID_*COND_*5 + 255)/256, 256, 0, stream>>>(kinw, kinwT, 1, HID_, COND_*5);
  k_mkWTs<<<(3*HID_*HID_*3 + 255)/256, 256, 0, stream>>>(krw1, krw1T, 3, HID_, HID_*3);
  k_mkWTs<<<(3*HID_*HID_*3 + 255)/256, 256, 0, stream>>>(krw2, krw2T, 3, HID_, HID_*3);
  k_mkWTs<<<(BCH_*HID_*3 + 255)/256, 256, 0, stream>>>(kbw, kbwT, 1, BCH_, HID_*3);
  k_mkWTs<<<(LAYERS_*C_*C_*3 + 255)/256, 256, 0, stream>>>(convw, convwT, LAYERS_, C_, C_*3);

  k_noise_cond<<<B_*COND_, 256, 0, stream>>>(ne, fw, fb, c, cond);
  k_kp_in<<<B_*(LMEL_/32), 256, 0, stream>>>(cond, kinwT, kinb, hkpa);
  // res chain: a -> b -> a -> b  (final in hkpb)
  k_kp_res2<<<B_*(LMEL_/32), 256, 0, stream>>>(hkpa, krw1T + 0*HID_*HID_*3, krb1 + 0*HID_,
                                               krw2T + 0*HID_*HID_*3, krb2 + 0*HID_, hkpb);
  k_kp_res2<<<B_*(LMEL_/32), 256, 0, stream>>>(hkpb, krw1T + 1*HID_*HID_*3, krb1 + 1*HID_,
                                               krw2T + 1*HID_*HID_*3, krb2 + 1*HID_, hkpa);
  k_kp_res2<<<B_*(LMEL_/32), 256, 0, stream>>>(hkpa, krw1T + 2*HID_*HID_*3, krb1 + 2*HID_,
                                               krw2T + 2*HID_*HID_*3, krb2 + 2*HID_, hkpb);
  k_kp_bias<<<B_*(LMEL_/16), 256, 0, stream>>>(hkpb, kbwT, kbb, biasb);
  k_upsample<<<B_*65, 256, 0, stream>>>(x, wtup, h);

  for (int i = 0; i < LAYERS_; i++) {
    const float* wci = convwT + i*C_*C_*3;
    switch (i) {
      case 0: k_dilconv<1 ><<<B_*(LAUD_/128), 256, 0, stream>>>(h, ad, wci, y2p); break;
      case 1: k_dilconv<3 ><<<B_*(LAUD_/128), 256, 0, stream>>>(h, ad, wci, y2p); break;
      case 2: k_dilconv<9 ><<<B_*(LAUD_/128), 256, 0, stream>>>(h, ad, wci, y2p); break;
      case 3: k_dilconv<27><<<B_*(LAUD_/128), 256, 0, stream>>>(h, ad, wci, y2p); break;
    }
    k_lvc_mfma<<<B_*128, 512, 0, stream>>>(hkpb, waf, kbt, biasb, y2p, ad, h, i);
  }
}

// Round 11
// 685.075 us; speedup vs baseline: 1.0115x; 1.0115x over previous
//
#include <hip/hip_runtime.h>
#include <math.h>

#define B_      4
#define C_      32
#define COND_   80
#define LMEL_   2048
#define HOP_    8
#define UP_     8
#define LAYERS_ 4
#define K_      3
#define HID_    64
#define KPK_    3
#define EMB_    512
#define LAUD_   (LMEL_*UP_)          // 16384
#define KCH_    (LAYERS_*C_*2*C_*K_) // 24576
#define BCH_    (LAYERS_*2*C_)       // 256
#define Y2S     (LAUD_ + 8)          // padded y2 row stride (+4 each side)

typedef short v8s __attribute__((ext_vector_type(8)));
typedef float v4f __attribute__((ext_vector_type(4)));

__device__ __forceinline__ float lrelu_(float v, float s) { return v >= 0.f ? v : s * v; }

__device__ __forceinline__ unsigned short f2bf(float f) {  // RNE float->bf16
  unsigned int x = __float_as_uint(f);
  unsigned int r = (x + 0x7FFFu + ((x >> 16) & 1u)) >> 16;
  return (unsigned short)r;
}

// ---------------------------------------------------------------- prep: generic slab transpose src[s][oc][ick] -> dst[s][ick][oc]
__global__ void k_mkWTs(const float* __restrict__ src, float* __restrict__ dst,
                        int S, int OC, int ICK) {
  int idx = blockIdx.x*256 + threadIdx.x;
  if (idx >= S*OC*ICK) return;
  int s = idx / (OC*ICK), rem = idx % (OC*ICK);
  int oc = rem / ICK, ick = rem % ICK;
  dst[s*OC*ICK + ick*OC + oc] = src[idx];
}

// ---------------------------------------------------------------- K1: noise + condition
__global__ void k_noise_cond(const float* __restrict__ ne, const float* __restrict__ fw,
                             const float* __restrict__ fb, const float* __restrict__ c,
                             float* __restrict__ cond) {
  int b = blockIdx.x / COND_;
  int cc = blockIdx.x % COND_;
  __shared__ float red[256];
  float p = 0.f;
  for (int j = threadIdx.x; j < EMB_; j += 256)
    p += ne[b*EMB_ + j] * fw[cc*EMB_ + j];
  red[threadIdx.x] = p;
  __syncthreads();
  for (int s = 128; s > 0; s >>= 1) {
    if (threadIdx.x < s) red[threadIdx.x] += red[threadIdx.x + s];
    __syncthreads();
  }
  float noise = red[0] + fb[cc];
  const float* cp = c + (b*COND_ + cc)*LMEL_;
  float* op = cond + (b*COND_ + cc)*LMEL_;
  for (int l = threadIdx.x; l < LMEL_; l += 256) op[l] = cp[l] + noise;
}

// ---------------------------------------------------------------- K2: KP input conv (80->64, k=5, pad=2, lrelu 0.1), T=32, wT[(cc*5+k)*64+ch]
__global__ __launch_bounds__(256) void k_kp_in(const float* __restrict__ cond, const float* __restrict__ wT,
                                               const float* __restrict__ bias, float* __restrict__ out) {
  const int T = 32;
  int b  = blockIdx.x / (LMEL_/T);
  int lb = (blockIdx.x % (LMEL_/T)) * T;
  __shared__ float sc[COND_][T + 4];
  for (int idx = threadIdx.x; idx < COND_*(T+4); idx += 256) {
    int cc = idx / (T+4), j = idx % (T+4);
    int l = lb + j - 2;
    sc[cc][j] = (l >= 0 && l < LMEL_) ? cond[(b*COND_ + cc)*LMEL_ + l] : 0.f;
  }
  __syncthreads();
  int ch = threadIdx.x & 63;
  int lq = threadIdx.x >> 6;  // 0..3, 8 l's each
  float acc[8];
#pragma unroll
  for (int ii = 0; ii < 8; ii++) acc[ii] = bias[ch];
  for (int cc = 0; cc < COND_; cc++) {
    float r[12];
#pragma unroll
    for (int j = 0; j < 12; j++) r[j] = sc[cc][lq*8 + j];
#pragma unroll
    for (int k = 0; k < 5; k++) {
      float wv = wT[(cc*5 + k)*64 + ch];
#pragma unroll
      for (int ii = 0; ii < 8; ii++) acc[ii] = fmaf(wv, r[ii + k], acc[ii]);
    }
  }
  float* op = out + (b*HID_ + ch)*LMEL_ + lb + lq*8;
#pragma unroll
  for (int ii = 0; ii < 8; ii++) acc[ii] = lrelu_(acc[ii], 0.1f);
  *reinterpret_cast<float4*>(&op[0]) = make_float4(acc[0], acc[1], acc[2], acc[3]);
  *reinterpret_cast<float4*>(&op[4]) = make_float4(acc[4], acc[5], acc[6], acc[7]);
}

// ---------------------------------------------------------------- K3: fused res pair: out = in + lrelu(conv2(lrelu(conv1(in))))
__global__ __launch_bounds__(256) void k_kp_res2(const float* __restrict__ in,
                                                 const float* __restrict__ w1T, const float* __restrict__ b1,
                                                 const float* __restrict__ w2T, const float* __restrict__ b2,
                                                 float* __restrict__ out) {
  const int T = 32;
  int b  = blockIdx.x / (LMEL_/T);
  int lb = (blockIdx.x % (LMEL_/T)) * T;
  __shared__ float si[HID_][38];   // cols lb-2 .. lb+33 (36 used)
  __shared__ float sr[HID_][38];   // intermediate r, cols lb-1 .. lb+32 (34 used)
  for (int idx = threadIdx.x; idx < HID_*36; idx += 256) {
    int cc = idx / 36, j = idx % 36;
    int l = lb - 2 + j;
    si[cc][j] = (l >= 0 && l < LMEL_) ? in[(b*HID_ + cc)*LMEL_ + l] : 0.f;
  }
  __syncthreads();
  int ch = threadIdx.x & 63;
  int lq = threadIdx.x >> 6;   // 0..3
  {
    float b1v = b1[ch];
    float a1[9];
#pragma unroll
    for (int jj = 0; jj < 9; jj++) a1[jj] = b1v;
    for (int cc = 0; cc < HID_; cc++) {
      float r[11];
#pragma unroll
      for (int j = 0; j < 11; j++) r[j] = si[cc][lq*9 + j];
#pragma unroll
      for (int k = 0; k < 3; k++) {
        float wv = w1T[(cc*3 + k)*64 + ch];
#pragma unroll
        for (int jj = 0; jj < 9; jj++) a1[jj] = fmaf(wv, r[jj + k], a1[jj]);
      }
    }
#pragma unroll
    for (int jj = 0; jj < 9; jj++) {
      int m = lq*9 + jj;
      if (m < 34) sr[ch][m] = lrelu_(a1[jj], 0.1f);
    }
  }
  __syncthreads();
  {
    float b2v = b2[ch];
    float a2[8];
#pragma unroll
    for (int jj = 0; jj < 8; jj++) a2[jj] = b2v;
    for (int cc = 0; cc < HID_; cc++) {
      float r[10];
#pragma unroll
      for (int j = 0; j < 10; j++) r[j] = sr[cc][lq*8 + j];
#pragma unroll
      for (int k = 0; k < 3; k++) {
        float wv = w2T[(cc*3 + k)*64 + ch];
#pragma unroll
        for (int jj = 0; jj < 8; jj++) a2[jj] = fmaf(wv, r[jj + k], a2[jj]);
      }
    }
    float* op = out + (b*HID_ + ch)*LMEL_ + lb + lq*8;
    float v[8];
#pragma unroll
    for (int jj = 0; jj < 8; jj++)
      v[jj] = si[ch][lq*8 + jj + 2] + lrelu_(a2[jj], 0.1f);
    *reinterpret_cast<float4*>(&op[0]) = make_float4(v[0], v[1], v[2], v[3]);
    *reinterpret_cast<float4*>(&op[4]) = make_float4(v[4], v[5], v[6], v[7]);
  }
}

// ---------------------------------------------------------------- K4: bias conv (64->256, k=3, pad=1), T=16, wT[(cc*3+k)*256+ch]
__global__ __launch_bounds__(256) void k_kp_bias(const float* __restrict__ in, const float* __restrict__ wT,
                                                 const float* __restrict__ bias, float* __restrict__ out) {
  const int T = 16;
  int b  = blockIdx.x / (LMEL_/T);
  int lb = (blockIdx.x % (LMEL_/T)) * T;
  __shared__ float si[HID_][T + 2];
  for (int idx = threadIdx.x; idx < HID_*(T+2); idx += 256) {
    int cc = idx / (T+2), j = idx % (T+2);
    int l = lb + j - 1;
    si[cc][j] = (l >= 0 && l < LMEL_) ? in[(b*HID_ + cc)*LMEL_ + l] : 0.f;
  }
  __syncthreads();
  int ch = threadIdx.x;  // 0..255
  float acc[T];
  float bv = bias[ch];
#pragma unroll
  for (int ii = 0; ii < T; ii++) acc[ii] = bv;
  for (int cc = 0; cc < HID_; cc++) {
    float w0 = wT[(cc*3 + 0)*256 + ch];
    float w1 = wT[(cc*3 + 1)*256 + ch];
    float w2 = wT[(cc*3 + 2)*256 + ch];
#pragma unroll
    for (int ii = 0; ii < T; ii++)
      acc[ii] = fmaf(w0, si[cc][ii], fmaf(w1, si[cc][ii+1], fmaf(w2, si[cc][ii+2], acc[ii])));
  }
  float* op = out + (b*BCH_ + ch)*LMEL_ + lb;
#pragma unroll
  for (int q = 0; q < 4; q++)
    *reinterpret_cast<float4*>(&op[q*4]) = make_float4(acc[q*4], acc[q*4+1], acc[q*4+2], acc[q*4+3]);
}

// ---------------------------------------------------------------- prep: upsample weight transpose -> wt[(ci*16+j)*32+co]
__global__ void k_mkUp(const float* __restrict__ upw, float* __restrict__ wt) {
  int idx = blockIdx.x*256 + threadIdx.x;
  if (idx >= C_*C_*16) return;
  int co = idx & 31, j = (idx >> 5) & 15, ci = idx >> 9;
  wt[idx] = upw[(ci*C_ + co)*16 + j];
}

// ---------------------------------------------------------------- K5: upsample (conv_transpose1d stride 8, k=16, pad=4), lrelu(x,0.2) input
#define UT 32
__global__ __launch_bounds__(256) void k_upsample(const float* __restrict__ x, const float* __restrict__ wt,
                                                  float* __restrict__ h) {
  int b  = blockIdx.x / 65;
  int s0 = (blockIdx.x % 65) * UT;
  __shared__ float sw[16384];          // [ci][j][co]
  __shared__ float sx[C_][33 + 3];
  for (int idx = threadIdx.x*4; idx < 16384; idx += 1024)
    *reinterpret_cast<float4*>(&sw[idx]) = *reinterpret_cast<const float4*>(&wt[idx]);
  for (int idx = threadIdx.x; idx < C_*33; idx += 256) {
    int ci = idx / 33, i = idx % 33;
    int s = s0 - 1 + i;
    float v = (s >= 0 && s < LMEL_) ? x[(b*C_ + ci)*LMEL_ + s] : 0.f;
    sx[ci][i] = lrelu_(v, 0.2f);
  }
  __syncthreads();
  int co = threadIdx.x & 31, sq = threadIdx.x >> 5;  // sq 0..7, 4 frames each
  float acc[4][8];
#pragma unroll
  for (int k = 0; k < 4; k++)
#pragma unroll
    for (int r = 0; r < 8; r++) acc[k][r] = 0.f;
  for (int ci = 0; ci < C_; ci++) {
    float xv[5];
#pragma unroll
    for (int m = 0; m < 5; m++) xv[m] = sx[ci][sq*4 + m];
    const float* wl = &sw[ci*512 + co];
#pragma unroll
    for (int r = 0; r < 8; r++) {
      float wa = wl[r*32];
      float wb = wl[(r+8)*32];
#pragma unroll
      for (int k = 0; k < 4; k++)
        acc[k][r] = fmaf(wa, sx[ci][sq*4 + k + 1], fmaf(wb, xv[k], acc[k][r]));
    }
  }
  float* op = h + ((size_t)b*C_ + co)*LAUD_;
#pragma unroll
  for (int k = 0; k < 4; k++) {
    int s1 = s0 + sq*4 + k;
    int lo = 8*s1 - 4;
    if (lo >= 0 && lo + 4 <= LAUD_)
      *reinterpret_cast<float4*>(&op[lo]) = make_float4(acc[k][0], acc[k][1], acc[k][2], acc[k][3]);
    if (lo >= -4 && lo + 8 <= LAUD_)
      *reinterpret_cast<float4*>(&op[lo+4]) = make_float4(acc[k][4], acc[k][5], acc[k][6], acc[k][7]);
  }
}

// ---------------------------------------------------------------- prep: A-fragment-ordered bf16 weights
__global__ void k_mkA(const float* __restrict__ kw, unsigned short* __restrict__ waf) {
  int idx = blockIdx.x*256 + threadIdx.x;
  if (idx >= KCH_*HID_*KPK_) return;   // 4,718,592
  int i    = idx & 7;
  int lane = (idx >> 3) & 63;
  int ks   = (idx >> 9) % 6;
  int tile = (idx / 3072) & 3;
  int rk   = idx / 12288;              // 0..383
  int layer = rk / 96, rem = rk % 96, ci = rem / 3, kk = rem % 3;
  int cout = tile*16 + (lane & 15);
  int j    = ks*32 + ((lane >> 4) << 3) + i;
  int row  = ((layer*32 + ci)*64 + cout)*3 + kk;
  waf[idx] = f2bf(kw[row*192 + j]);
}

// ---------------------------------------------------------------- prep: kernel-conv bias reordered
__global__ void k_mkKbT(const float* __restrict__ kb, float* __restrict__ kbt) {
  int idx = blockIdx.x*256 + threadIdx.x;
  if (idx >= KCH_) return;             // 24576
  int cr = idx & 15, tile = (idx >> 4) & 3, rk = idx >> 6;
  int layer = rk / 96, rem = rk % 96, ci = rem / 3, kk = rem % 3;
  int cout = tile*16 + cr;
  kbt[idx] = kb[((layer*32 + ci)*64 + cout)*3 + kk];
}

// ---------------------------------------------------------------- K6: dilated conv (32->32, k=3) on lrelu(h+ad,0.2), out lrelu 0.2, T=128
// Writes into PADDED y2 buffer (row stride Y2S, data at +4); edge blocks zero the pads.
template<int DIL>
__global__ __launch_bounds__(256) void k_dilconv(const float* __restrict__ h, const float* __restrict__ ad,
                                                 const float* __restrict__ wT, float* __restrict__ y2p) {
  const int T = 128;
  int b  = blockIdx.x / (LAUD_/T);
  int tb = (blockIdx.x % (LAUD_/T)) * T;
  const int W = T + 2*DIL;
  __shared__ float ss[C_][T + 2*27 + 4];
  for (int idx = threadIdx.x; idx < C_*W; idx += 256) {
    int ci = idx / W, j = idx % W;
    int t = tb - DIL + j;
    float v = 0.f;
    if (t >= 0 && t < LAUD_) {
      int g = (b*C_ + ci)*LAUD_ + t;
      v = h[g] + ad[g];
    }
    ss[ci][j] = lrelu_(v, 0.2f);
  }
  // zero y2 pads (left pad at row*Y2S+0..3, right pad at row*Y2S+4+LAUD..+3)
  if (tb == 0 && threadIdx.x < 128) {
    int ci = threadIdx.x >> 2, q = threadIdx.x & 3;
    y2p[(size_t)(b*C_ + ci)*Y2S + q] = 0.f;
  }
  if (tb == LAUD_ - T && threadIdx.x < 128) {
    int ci = threadIdx.x >> 2, q = threadIdx.x & 3;
    y2p[(size_t)(b*C_ + ci)*Y2S + 4 + LAUD_ + q] = 0.f;
  }
  __syncthreads();
  int co = threadIdx.x & 31, tq = threadIdx.x >> 5;
  float acc[16];
#pragma unroll
  for (int ii = 0; ii < 16; ii++) acc[ii] = 0.f;
  for (int ci = 0; ci < C_; ci++) {
    float w0 = wT[(ci*3 + 0)*32 + co];
    float w1 = wT[(ci*3 + 1)*32 + co];
    float w2 = wT[(ci*3 + 2)*32 + co];
#pragma unroll
    for (int ii = 0; ii < 16; ii++) {
      int tl = tq*16 + ii;
      acc[ii] = fmaf(w0, ss[ci][tl], fmaf(w1, ss[ci][tl + DIL], fmaf(w2, ss[ci][tl + 2*DIL], acc[ii])));
    }
  }
  float* op = y2p + (size_t)(b*C_ + co)*Y2S + 4 + tb + tq*16;
#pragma unroll
  for (int ii = 0; ii < 16; ii++) acc[ii] = lrelu_(acc[ii], 0.2f);
#pragma unroll
  for (int q = 0; q < 4; q++)
    *reinterpret_cast<float4*>(&op[q*4]) = make_float4(acc[q*4], acc[q*4+1], acc[q*4+2], acc[q*4+3]);
}

// ---------------------------------------------------------------- K7: MFMA-fused KP-GEMM + LVC + gate + h update
// 512 thr, 8 waves = wq(0..3 ci-quarters) x tp(0..1). Block owns tiles {variant, variant+2}.
// y2 read DIRECT from padded global (no LDS stage); shh aliases red (barrier-separated).
// LDS = red 16896 + FB 12288 = 29184 B -> 2+ blocks/CU by every resource.
// launch_bounds min-waves stays 2 ((512,4) forces 64-reg arch split -> spill, r5/r6).
#define FR2 32
#define RED(t, l, rs) red[(((t)*64 + (l))*33) + (rs)]

#define LOADY(SYR, TBASE)                                                        \
  {                                                                              \
    const float* yp = yr + (TBASE);                                              \
    float4 qa = *reinterpret_cast<const float4*>(yp - 4);                        \
    float4 qb = *reinterpret_cast<const float4*>(yp);                            \
    float4 qc = *reinterpret_cast<const float4*>(yp + 4);                        \
    float4 qd = *reinterpret_cast<const float4*>(yp + 8);                        \
    SYR[0] = qa.w;                                                               \
    SYR[1] = qb.x; SYR[2] = qb.y; SYR[3] = qb.z; SYR[4] = qb.w;                  \
    SYR[5] = qc.x; SYR[6] = qc.y; SYR[7] = qc.z; SYR[8] = qc.w;                  \
    SYR[9] = qd.x; SYR[10] = qd.y; SYR[11] = qd.z;                               \
  }

#define EPILOGUE(G, OO)                                                          \
  {                                                                              \
    __syncthreads();                                                             \
    if (wq == 3) {                                                               \
      _Pragma("unroll") for (int r = 0; r < 4; r++)                              \
        _Pragma("unroll") for (int s = 0; s < 8; s++)                            \
          RED(tp, lane, r*8 + s) = OO[r][s];                                     \
    }                                                                            \
    __syncthreads();                                                             \
    if (wq == 2) {                                                               \
      _Pragma("unroll") for (int r = 0; r < 4; r++)                              \
        _Pragma("unroll") for (int s = 0; s < 8; s++)                            \
          RED(tp, lane, r*8 + s) += OO[r][s];                                    \
    }                                                                            \
    __syncthreads();                                                             \
    if (wq == 1) {                                                               \
      _Pragma("unroll") for (int r = 0; r < 4; r++)                              \
        _Pragma("unroll") for (int s = 0; s < 8; s++)                            \
          RED(tp, lane, r*8 + s) += OO[r][s];                                    \
    }                                                                            \
    __syncthreads();                                                             \
    if (wq == 0) {                                                               \
      _Pragma("unroll") for (int r = 0; r < 4; r++) {                            \
        int cout = tile*16 + ((lane >> 4) << 2) + r;                             \
        float bv = biasb[((size_t)b*BCH_ + layer*2*C_ + cout)*LMEL_ + l0 + G*16 + f]; \
        _Pragma("unroll") for (int s = 0; s < 8; s++)                            \
          OO[r][s] += RED(tp, lane, r*8 + s) + bv;                               \
      }                                                                          \
      if (tp == 1) {                                                             \
        _Pragma("unroll") for (int r = 0; r < 4; r++)                            \
          _Pragma("unroll") for (int s = 0; s < 8; s++)                          \
            RED(1, lane, r*8 + s) = OO[r][s];                                    \
      }                                                                          \
    }                                                                            \
    __syncthreads();                                                             \
    if (wq == 0 && tp == 0) {                                                    \
      _Pragma("unroll") for (int r = 0; r < 4; r++) {                            \
        int cout = tile*16 + ((lane >> 4) << 2) + r;                             \
        size_t base = ((size_t)b*C_ + cout)*LAUD_ + (size_t)(l0 + G*16 + f)*HOP_;\
        float4 h0 = *reinterpret_cast<const float4*>(&h[base]);                  \
        float4 h1 = *reinterpret_cast<const float4*>(&h[base + 4]);              \
        float4 a0 = *reinterpret_cast<const float4*>(&ad[base]);                 \
        float4 a1 = *reinterpret_cast<const float4*>(&ad[base + 4]);             \
        float outv[8];                                                           \
        _Pragma("unroll") for (int s = 0; s < 8; s++) {                          \
          float v  = OO[r][s];                                                   \
          float tv = RED(1, lane, r*8 + s);                                      \
          float sig = 1.f / (1.f + __expf(-v));                                  \
          float th  = 1.f - 2.f / (1.f + __expf(2.f*tv));                        \
          float hv = (s < 4) ? ((const float*)&h0)[s] : ((const float*)&h1)[s-4];\
          float av = (s < 4) ? ((const float*)&a0)[s] : ((const float*)&a1)[s-4];\
          outv[s] = hv + av + sig * th;                                          \
        }                                                                        \
        *reinterpret_cast<float4*>(&h[base])     = make_float4(outv[0], outv[1], outv[2], outv[3]); \
        *reinterpret_cast<float4*>(&h[base + 4]) = make_float4(outv[4], outv[5], outv[6], outv[7]); \
      }                                                                          \
    }                                                                            \
  }

__global__ __launch_bounds__(512, 2) void k_lvc_mfma(
    const float* __restrict__ hkp, const unsigned short* __restrict__ waf,
    const float* __restrict__ kbt, const float* __restrict__ biasb,
    const float* __restrict__ y2p, const float* __restrict__ ad,
    float* __restrict__ h, int layer) {
  int b  = blockIdx.x >> 7;               // 64 frame-tiles x 2 variants
  int r7 = blockIdx.x & 127;
  int l0 = (r7 >> 1) * FR2;
  int variant = r7 & 1;

  __shared__ __align__(16) float red[2*64*33];            // 16896 B; shh aliases front
  __shared__ __align__(16) unsigned short FB[2*6*64*8];   // 12288 B
  float* shh = red;                                       // [HID_][34], 8704 B, dead after FB build

  int tid = threadIdx.x;
  for (int idx = tid; idx < HID_*34; idx += 512) {
    int hh = idx / 34, j = idx % 34;
    int l = l0 - 1 + j;
    shh[hh*34 + j] = (l >= 0 && l < LMEL_) ? hkp[(b*HID_ + hh)*LMEL_ + l] : 0.f;
  }
  __syncthreads();
  for (int idx = tid; idx < 6144; idx += 512) {
    int i = idx & 7, lane2 = (idx >> 3) & 63, gk = idx >> 9;  // gk = g*6+ks
    int ks = gk % 6, g = gk / 6;
    int k = ks*32 + ((lane2 >> 4) << 3) + i;
    int col = lane2 & 15;
    int hh = k / 3, q = k - hh*3;
    FB[idx] = f2bf(shh[hh*34 + g*16 + col + q]);
  }
  __syncthreads();

  int wave = tid >> 6, lane = tid & 63;
  int tp = wave & 1, wq = wave >> 1;      // tp: tile-pair member, wq: ci-quarter
  int tile = variant + 2*tp;              // {v, v+2}: sigmoid & tanh halves
  int f = lane & 15;

  v8s bfrA[6], bfrB[6];
#pragma unroll
  for (int ks = 0; ks < 6; ks++) {
    bfrA[ks] = *reinterpret_cast<const v8s*>(&FB[(ks*64 + lane)*8]);
    bfrB[ks] = *reinterpret_cast<const v8s*>(&FB[((6 + ks)*64 + lane)*8]);
  }

  float o0[4][8], o1[4][8];
#pragma unroll
  for (int r = 0; r < 4; r++)
#pragma unroll
    for (int s = 0; s < 8; s++) { o0[r][s] = 0.f; o1[r][s] = 0.f; }

  const int rk0 = layer*96 + wq*24;       // 8 ci per quarter = 24 rk
  const unsigned short* wbase = waf + ((size_t)rk0*4 + tile)*3072 + lane*8;
  const float* kbbase = kbt + (rk0*4 + tile)*16 + ((lane >> 4) << 2);
  const float* ybase = y2p + ((size_t)(b*C_ + wq*8))*Y2S + 4;
  const int t0 = (l0 + f)*8;              // g=0 sample base (aligned quad at t0-4)
  const int t1 = (l0 + 16 + f)*8;         // g=1

  for (int ciq = 0; ciq < 8; ciq++) {
    const float* yr = ybase + (size_t)ciq*Y2S;
    float syr0[12], syr1[12];
    LOADY(syr0, t0)
    LOADY(syr1, t1)
#pragma unroll
    for (int kk = 0; kk < 3; kk++) {
      const unsigned short* wp = wbase + (size_t)(ciq*3 + kk)*12288;
      v4f acc0 = {0.f, 0.f, 0.f, 0.f};
      v4f acc1 = {0.f, 0.f, 0.f, 0.f};
#pragma unroll
      for (int ks = 0; ks < 6; ks++) {
        v8s a = *reinterpret_cast<const v8s*>(wp + ks*512);
        acc0 = __builtin_amdgcn_mfma_f32_16x16x32_bf16(a, bfrA[ks], acc0, 0, 0, 0);
        acc1 = __builtin_amdgcn_mfma_f32_16x16x32_bf16(a, bfrB[ks], acc1, 0, 0, 0);
      }
      float4 kb4 = *reinterpret_cast<const float4*>(kbbase + (ciq*3 + kk)*64);
#pragma unroll
      for (int r = 0; r < 4; r++) {
        float k0 = acc0[r] + ((const float*)&kb4)[r];
        float k1 = acc1[r] + ((const float*)&kb4)[r];
#pragma unroll
        for (int s = 0; s < 8; s++) {
          o0[r][s] = fmaf(k0, syr0[kk + s], o0[r][s]);
          o1[r][s] = fmaf(k1, syr1[kk + s], o1[r][s]);
        }
      }
    }
  }

  EPILOGUE(0, o0)
  EPILOGUE(1, o1)
}

// ---------------------------------------------------------------- launcher
extern "C" void kernel_launch(void* const* d_in, const int* in_sizes, int n_in,
                              void* d_out, int out_size, void* d_ws, size_t ws_size,
                              hipStream_t stream) {
  const float* x     = (const float*)d_in[0];
  const float* ad    = (const float*)d_in[1];
  const float* c     = (const float*)d_in[2];
  const float* ne    = (const float*)d_in[3];
  const float* fw    = (const float*)d_in[4];
  const float* fb    = (const float*)d_in[5];
  const float* upw   = (const float*)d_in[6];
  const float* convw = (const float*)d_in[7];
  const float* kinw  = (const float*)d_in[8];
  const float* kinb  = (const float*)d_in[9];
  const float* krw1  = (const float*)d_in[10];
  const float* krb1  = (const float*)d_in[11];
  const float* krw2  = (const float*)d_in[12];
  const float* krb2  = (const float*)d_in[13];
  const float* kkw   = (const float*)d_in[14];
  const float* kkb   = (const float*)d_in[15];
  const float* kbw   = (const float*)d_in[16];
  const float* kbb   = (const float*)d_in[17];
  float* h = (float*)d_out;

  float* ws = (float*)d_ws;
  float* cond   = ws; ws += B_*COND_*LMEL_;
  float* hkpa   = ws; ws += B_*HID_*LMEL_;
  float* hkpb   = ws; ws += B_*HID_*LMEL_;
  float* biasb  = ws; ws += B_*BCH_*LMEL_;
  float* y2p    = ws; ws += B_*C_*Y2S;
  float* kbt    = ws; ws += KCH_;
  float* wtup   = ws; ws += C_*C_*16;
  float* kinwT  = ws; ws += HID_*COND_*5;
  float* krw1T  = ws; ws += 3*HID_*HID_*3;
  float* krw2T  = ws; ws += 3*HID_*HID_*3;
  float* kbwT   = ws; ws += BCH_*HID_*3;
  float* convwT = ws; ws += LAYERS_*C_*C_*3;
  unsigned short* waf = (unsigned short*)ws; ws += (KCH_*HID_*KPK_)/2;

  k_mkA<<<(KCH_*HID_*KPK_ + 255)/256, 256, 0, stream>>>(kkw, waf);
  k_mkKbT<<<(KCH_ + 255)/256, 256, 0, stream>>>(kkb, kbt);
  k_mkUp<<<(C_*C_*16 + 255)/256, 256, 0, stream>>>(upw, wtup);
  k_mkWTs<<<(HID_*COND_*5 + 255)/256, 256, 0, stream>>>(kinw, kinwT, 1, HID_, COND_*5);
  k_mkWTs<<<(3*HID_*HID_*3 + 255)/256, 256, 0, stream>>>(krw1, krw1T, 3, HID_, HID_*3);
  k_mkWTs<<<(3*HID_*HID_*3 + 255)/256, 256, 0, stream>>>(krw2, krw2T, 3, HID_, HID_*3);
  k_mkWTs<<<(BCH_*HID_*3 + 255)/256, 256, 0, stream>>>(kbw, kbwT, 1, BCH_, HID_*3);
  k_mkWTs<<<(LAYERS_*C_*C_*3 + 255)/256, 256, 0, stream>>>(convw, convwT, LAYERS_, C_, C_*3);

  k_noise_cond<<<B_*COND_, 256, 0, stream>>>(ne, fw, fb, c, cond);
  k_kp_in<<<B_*(LMEL_/32), 256, 0, stream>>>(cond, kinwT, kinb, hkpa);
  // res chain: a -> b -> a -> b  (final in hkpb)
  k_kp_res2<<<B_*(LMEL_/32), 256, 0, stream>>>(hkpa, krw1T + 0*HID_*HID_*3, krb1 + 0*HID_,
                                               krw2T + 0*HID_*HID_*3, krb2 + 0*HID_, hkpb);
  k_kp_res2<<<B_*(LMEL_/32), 256, 0, stream>>>(hkpb, krw1T + 1*HID_*HID_*3, krb1 + 1*HID_,
                                               krw2T + 1*HID_*HID_*3, krb2 + 1*HID_, hkpa);
  k_kp_res2<<<B_*(LMEL_/32), 256, 0, stream>>>(hkpa, krw1T + 2*HID_*HID_*3, krb1 + 2*HID_,
                                               krw2T + 2*HID_*HID_*3, krb2 + 2*HID_, hkpb);
  k_kp_bias<<<B_*(LMEL_/16), 256, 0, stream>>>(hkpb, kbwT, kbb, biasb);
  k_upsample<<<B_*65, 256, 0, stream>>>(x, wtup, h);

  for (int i = 0; i < LAYERS_; i++) {
    const float* wci = convwT + i*C_*C_*3;
    switch (i) {
      case 0: k_dilconv<1 ><<<B_*(LAUD_/128), 256, 0, stream>>>(h, ad, wci, y2p); break;
      case 1: k_dilconv<3 ><<<B_*(LAUD_/128), 256, 0, stream>>>(h, ad, wci, y2p); break;
      case 2: k_dilconv<9 ><<<B_*(LAUD_/128), 256, 0, stream>>>(h, ad, wci, y2p); break;
      case 3: k_dilconv<27><<<B_*(LAUD_/128), 256, 0, stream>>>(h, ad, wci, y2p); break;
    }
    k_lvc_mfma<<<B_*128, 512, 0, stream>>>(hkpb, waf, kbt, biasb, y2p, ad, h, i);
  }
}

// Round 12
// 534.105 us; speedup vs baseline: 1.2974x; 1.2827x over previous
//
#include <hip/hip_runtime.h>
#include <math.h>

#define B_      4
#define C_      32
#define COND_   80
#define LMEL_   2048
#define HOP_    8
#define UP_     8
#define LAYERS_ 4
#define K_      3
#define HID_    64
#define KPK_    3
#define EMB_    512
#define LAUD_   (LMEL_*UP_)          // 16384
#define KCH_    (LAYERS_*C_*2*C_*K_) // 24576
#define BCH_    (LAYERS_*2*C_)       // 256
#define Y2S     (LAUD_ + 8)          // padded y2 row stride (+4 each side)

typedef short v8s __attribute__((ext_vector_type(8)));
typedef float v4f __attribute__((ext_vector_type(4)));

__device__ __forceinline__ float lrelu_(float v, float s) { return v >= 0.f ? v : s * v; }

__device__ __forceinline__ unsigned short f2bf(float f) {  // RNE float->bf16
  unsigned int x = __float_as_uint(f);
  unsigned int r = (x + 0x7FFFu + ((x >> 16) & 1u)) >> 16;
  return (unsigned short)r;
}

// async global->LDS DMA, 16B per lane (guide §5: dest = wave-uniform base + lane*16)
#define GLOAD16(GSRC, LDST)                                              \
  __builtin_amdgcn_global_load_lds(                                     \
      (const __attribute__((address_space(1))) unsigned int*)(GSRC),    \
      (__attribute__((address_space(3))) unsigned int*)(LDST), 16, 0, 0)

// ---------------------------------------------------------------- prep: generic slab transpose src[s][oc][ick] -> dst[s][ick][oc]
__global__ void k_mkWTs(const float* __restrict__ src, float* __restrict__ dst,
                        int S, int OC, int ICK) {
  int idx = blockIdx.x*256 + threadIdx.x;
  if (idx >= S*OC*ICK) return;
  int s = idx / (OC*ICK), rem = idx % (OC*ICK);
  int oc = rem / ICK, ick = rem % ICK;
  dst[s*OC*ICK + ick*OC + oc] = src[idx];
}

// ---------------------------------------------------------------- K1: noise + condition
__global__ void k_noise_cond(const float* __restrict__ ne, const float* __restrict__ fw,
                             const float* __restrict__ fb, const float* __restrict__ c,
                             float* __restrict__ cond) {
  int b = blockIdx.x / COND_;
  int cc = blockIdx.x % COND_;
  __shared__ float red[256];
  float p = 0.f;
  for (int j = threadIdx.x; j < EMB_; j += 256)
    p += ne[b*EMB_ + j] * fw[cc*EMB_ + j];
  red[threadIdx.x] = p;
  __syncthreads();
  for (int s = 128; s > 0; s >>= 1) {
    if (threadIdx.x < s) red[threadIdx.x] += red[threadIdx.x + s];
    __syncthreads();
  }
  float noise = red[0] + fb[cc];
  const float* cp = c + (b*COND_ + cc)*LMEL_;
  float* op = cond + (b*COND_ + cc)*LMEL_;
  for (int l = threadIdx.x; l < LMEL_; l += 256) op[l] = cp[l] + noise;
}

// ---------------------------------------------------------------- K2: KP input conv (80->64, k=5, pad=2, lrelu 0.1), T=32, wT[(cc*5+k)*64+ch]
__global__ __launch_bounds__(256) void k_kp_in(const float* __restrict__ cond, const float* __restrict__ wT,
                                               const float* __restrict__ bias, float* __restrict__ out) {
  const int T = 32;
  int b  = blockIdx.x / (LMEL_/T);
  int lb = (blockIdx.x % (LMEL_/T)) * T;
  __shared__ float sc[COND_][T + 4];
  for (int idx = threadIdx.x; idx < COND_*(T+4); idx += 256) {
    int cc = idx / (T+4), j = idx % (T+4);
    int l = lb + j - 2;
    sc[cc][j] = (l >= 0 && l < LMEL_) ? cond[(b*COND_ + cc)*LMEL_ + l] : 0.f;
  }
  __syncthreads();
  int ch = threadIdx.x & 63;
  int lq = threadIdx.x >> 6;  // 0..3, 8 l's each
  float acc[8];
#pragma unroll
  for (int ii = 0; ii < 8; ii++) acc[ii] = bias[ch];
  for (int cc = 0; cc < COND_; cc++) {
    float r[12];
#pragma unroll
    for (int j = 0; j < 12; j++) r[j] = sc[cc][lq*8 + j];
#pragma unroll
    for (int k = 0; k < 5; k++) {
      float wv = wT[(cc*5 + k)*64 + ch];
#pragma unroll
      for (int ii = 0; ii < 8; ii++) acc[ii] = fmaf(wv, r[ii + k], acc[ii]);
    }
  }
  float* op = out + (b*HID_ + ch)*LMEL_ + lb + lq*8;
#pragma unroll
  for (int ii = 0; ii < 8; ii++) acc[ii] = lrelu_(acc[ii], 0.1f);
  *reinterpret_cast<float4*>(&op[0]) = make_float4(acc[0], acc[1], acc[2], acc[3]);
  *reinterpret_cast<float4*>(&op[4]) = make_float4(acc[4], acc[5], acc[6], acc[7]);
}

// ---------------------------------------------------------------- K3: fused res pair: out = in + lrelu(conv2(lrelu(conv1(in))))
__global__ __launch_bounds__(256) void k_kp_res2(const float* __restrict__ in,
                                                 const float* __restrict__ w1T, const float* __restrict__ b1,
                                                 const float* __restrict__ w2T, const float* __restrict__ b2,
                                                 float* __restrict__ out) {
  const int T = 32;
  int b  = blockIdx.x / (LMEL_/T);
  int lb = (blockIdx.x % (LMEL_/T)) * T;
  __shared__ float si[HID_][38];   // cols lb-2 .. lb+33 (36 used)
  __shared__ float sr[HID_][38];   // intermediate r, cols lb-1 .. lb+32 (34 used)
  for (int idx = threadIdx.x; idx < HID_*36; idx += 256) {
    int cc = idx / 36, j = idx % 36;
    int l = lb - 2 + j;
    si[cc][j] = (l >= 0 && l < LMEL_) ? in[(b*HID_ + cc)*LMEL_ + l] : 0.f;
  }
  __syncthreads();
  int ch = threadIdx.x & 63;
  int lq = threadIdx.x >> 6;   // 0..3
  {
    float b1v = b1[ch];
    float a1[9];
#pragma unroll
    for (int jj = 0; jj < 9; jj++) a1[jj] = b1v;
    for (int cc = 0; cc < HID_; cc++) {
      float r[11];
#pragma unroll
      for (int j = 0; j < 11; j++) r[j] = si[cc][lq*9 + j];
#pragma unroll
      for (int k = 0; k < 3; k++) {
        float wv = w1T[(cc*3 + k)*64 + ch];
#pragma unroll
        for (int jj = 0; jj < 9; jj++) a1[jj] = fmaf(wv, r[jj + k], a1[jj]);
      }
    }
#pragma unroll
    for (int jj = 0; jj < 9; jj++) {
      int m = lq*9 + jj;
      if (m < 34) sr[ch][m] = lrelu_(a1[jj], 0.1f);
    }
  }
  __syncthreads();
  {
    float b2v = b2[ch];
    float a2[8];
#pragma unroll
    for (int jj = 0; jj < 8; jj++) a2[jj] = b2v;
    for (int cc = 0; cc < HID_; cc++) {
      float r[10];
#pragma unroll
      for (int j = 0; j < 10; j++) r[j] = sr[cc][lq*8 + j];
#pragma unroll
      for (int k = 0; k < 3; k++) {
        float wv = w2T[(cc*3 + k)*64 + ch];
#pragma unroll
        for (int jj = 0; jj < 8; jj++) a2[jj] = fmaf(wv, r[jj + k], a2[jj]);
      }
    }
    float* op = out + (b*HID_ + ch)*LMEL_ + lb + lq*8;
    float v[8];
#pragma unroll
    for (int jj = 0; jj < 8; jj++)
      v[jj] = si[ch][lq*8 + jj + 2] + lrelu_(a2[jj], 0.1f);
    *reinterpret_cast<float4*>(&op[0]) = make_float4(v[0], v[1], v[2], v[3]);
    *reinterpret_cast<float4*>(&op[4]) = make_float4(v[4], v[5], v[6], v[7]);
  }
}

// ---------------------------------------------------------------- K4: bias conv (64->256, k=3, pad=1), T=16, wT[(cc*3+k)*256+ch]
__global__ __launch_bounds__(256) void k_kp_bias(const float* __restrict__ in, const float* __restrict__ wT,
                                                 const float* __restrict__ bias, float* __restrict__ out) {
  const int T = 16;
  int b  = blockIdx.x / (LMEL_/T);
  int lb = (blockIdx.x % (LMEL_/T)) * T;
  __shared__ float si[HID_][T + 2];
  for (int idx = threadIdx.x; idx < HID_*(T+2); idx += 256) {
    int cc = idx / (T+2), j = idx % (T+2);
    int l = lb + j - 1;
    si[cc][j] = (l >= 0 && l < LMEL_) ? in[(b*HID_ + cc)*LMEL_ + l] : 0.f;
  }
  __syncthreads();
  int ch = threadIdx.x;  // 0..255
  float acc[T];
  float bv = bias[ch];
#pragma unroll
  for (int ii = 0; ii < T; ii++) acc[ii] = bv;
  for (int cc = 0; cc < HID_; cc++) {
    float w0 = wT[(cc*3 + 0)*256 + ch];
    float w1 = wT[(cc*3 + 1)*256 + ch];
    float w2 = wT[(cc*3 + 2)*256 + ch];
#pragma unroll
    for (int ii = 0; ii < T; ii++)
      acc[ii] = fmaf(w0, si[cc][ii], fmaf(w1, si[cc][ii+1], fmaf(w2, si[cc][ii+2], acc[ii])));
  }
  float* op = out + (b*BCH_ + ch)*LMEL_ + lb;
#pragma unroll
  for (int q = 0; q < 4; q++)
    *reinterpret_cast<float4*>(&op[q*4]) = make_float4(acc[q*4], acc[q*4+1], acc[q*4+2], acc[q*4+3]);
}

// ---------------------------------------------------------------- prep: upsample weight transpose -> wt[(ci*16+j)*32+co]
__global__ void k_mkUp(const float* __restrict__ upw, float* __restrict__ wt) {
  int idx = blockIdx.x*256 + threadIdx.x;
  if (idx >= C_*C_*16) return;
  int co = idx & 31, j = (idx >> 5) & 15, ci = idx >> 9;
  wt[idx] = upw[(ci*C_ + co)*16 + j];
}

// ---------------------------------------------------------------- K5: upsample (conv_transpose1d stride 8, k=16, pad=4), lrelu(x,0.2) input
#define UT 32
__global__ __launch_bounds__(256) void k_upsample(const float* __restrict__ x, const float* __restrict__ wt,
                                                  float* __restrict__ h) {
  int b  = blockIdx.x / 65;
  int s0 = (blockIdx.x % 65) * UT;
  __shared__ float sw[16384];          // [ci][j][co]
  __shared__ float sx[C_][33 + 3];
  for (int idx = threadIdx.x*4; idx < 16384; idx += 1024)
    *reinterpret_cast<float4*>(&sw[idx]) = *reinterpret_cast<const float4*>(&wt[idx]);
  for (int idx = threadIdx.x; idx < C_*33; idx += 256) {
    int ci = idx / 33, i = idx % 33;
    int s = s0 - 1 + i;
    float v = (s >= 0 && s < LMEL_) ? x[(b*C_ + ci)*LMEL_ + s] : 0.f;
    sx[ci][i] = lrelu_(v, 0.2f);
  }
  __syncthreads();
  int co = threadIdx.x & 31, sq = threadIdx.x >> 5;  // sq 0..7, 4 frames each
  float acc[4][8];
#pragma unroll
  for (int k = 0; k < 4; k++)
#pragma unroll
    for (int r = 0; r < 8; r++) acc[k][r] = 0.f;
  for (int ci = 0; ci < C_; ci++) {
    float xv[5];
#pragma unroll
    for (int m = 0; m < 5; m++) xv[m] = sx[ci][sq*4 + m];
    const float* wl = &sw[ci*512 + co];
#pragma unroll
    for (int r = 0; r < 8; r++) {
      float wa = wl[r*32];
      float wb = wl[(r+8)*32];
#pragma unroll
      for (int k = 0; k < 4; k++)
        acc[k][r] = fmaf(wa, xv[k+1], fmaf(wb, xv[k], acc[k][r]));
    }
  }
  float* op = h + ((size_t)b*C_ + co)*LAUD_;
#pragma unroll
  for (int k = 0; k < 4; k++) {
    int s1 = s0 + sq*4 + k;
    int lo = 8*s1 - 4;
    if (lo >= 0 && lo + 4 <= LAUD_)
      *reinterpret_cast<float4*>(&op[lo]) = make_float4(acc[k][0], acc[k][1], acc[k][2], acc[k][3]);
    if (lo >= -4 && lo + 8 <= LAUD_)
      *reinterpret_cast<float4*>(&op[lo+4]) = make_float4(acc[k][4], acc[k][5], acc[k][6], acc[k][7]);
  }
}

// ---------------------------------------------------------------- prep: A-fragment-ordered bf16 weights
__global__ void k_mkA(const float* __restrict__ kw, unsigned short* __restrict__ waf) {
  int idx = blockIdx.x*256 + threadIdx.x;
  if (idx >= KCH_*HID_*KPK_) return;   // 4,718,592
  int i    = idx & 7;
  int lane = (idx >> 3) & 63;
  int ks   = (idx >> 9) % 6;
  int tile = (idx / 3072) & 3;
  int rk   = idx / 12288;              // 0..383
  int layer = rk / 96, rem = rk % 96, ci = rem / 3, kk = rem % 3;
  int cout = tile*16 + (lane & 15);
  int j    = ks*32 + ((lane >> 4) << 3) + i;
  int row  = ((layer*32 + ci)*64 + cout)*3 + kk;
  waf[idx] = f2bf(kw[row*192 + j]);
}

// ---------------------------------------------------------------- prep: kernel-conv bias reordered
__global__ void k_mkKbT(const float* __restrict__ kb, float* __restrict__ kbt) {
  int idx = blockIdx.x*256 + threadIdx.x;
  if (idx >= KCH_) return;             // 24576
  int cr = idx & 15, tile = (idx >> 4) & 3, rk = idx >> 6;
  int layer = rk / 96, rem = rk % 96, ci = rem / 3, kk = rem % 3;
  int cout = tile*16 + cr;
  kbt[idx] = kb[((layer*32 + ci)*64 + cout)*3 + kk];
}

// ---------------------------------------------------------------- K6: dilated conv (32->32, k=3) on lrelu(h+ad,0.2), out lrelu 0.2, T=128
// Writes into PADDED y2 buffer (row stride Y2S, data at +4); edge blocks zero the pads.
template<int DIL>
__global__ __launch_bounds__(256) void k_dilconv(const float* __restrict__ h, const float* __restrict__ ad,
                                                 const float* __restrict__ wT, float* __restrict__ y2p) {
  const int T = 128;
  int b  = blockIdx.x / (LAUD_/T);
  int tb = (blockIdx.x % (LAUD_/T)) * T;
  const int W = T + 2*DIL;
  __shared__ float ss[C_][T + 2*27 + 4];
  for (int idx = threadIdx.x; idx < C_*W; idx += 256) {
    int ci = idx / W, j = idx % W;
    int t = tb - DIL + j;
    float v = 0.f;
    if (t >= 0 && t < LAUD_) {
      int g = (b*C_ + ci)*LAUD_ + t;
      v = h[g] + ad[g];
    }
    ss[ci][j] = lrelu_(v, 0.2f);
  }
  // zero y2 pads
  if (tb == 0 && threadIdx.x < 128) {
    int ci = threadIdx.x >> 2, q = threadIdx.x & 3;
    y2p[(size_t)(b*C_ + ci)*Y2S + q] = 0.f;
  }
  if (tb == LAUD_ - T && threadIdx.x < 128) {
    int ci = threadIdx.x >> 2, q = threadIdx.x & 3;
    y2p[(size_t)(b*C_ + ci)*Y2S + 4 + LAUD_ + q] = 0.f;
  }
  __syncthreads();
  int co = threadIdx.x & 31, tq = threadIdx.x >> 5;
  float acc[16];
#pragma unroll
  for (int ii = 0; ii < 16; ii++) acc[ii] = 0.f;
  for (int ci = 0; ci < C_; ci++) {
    float w0 = wT[(ci*3 + 0)*32 + co];
    float w1 = wT[(ci*3 + 1)*32 + co];
    float w2 = wT[(ci*3 + 2)*32 + co];
#pragma unroll
    for (int ii = 0; ii < 16; ii++) {
      int tl = tq*16 + ii;
      acc[ii] = fmaf(w0, ss[ci][tl], fmaf(w1, ss[ci][tl + DIL], fmaf(w2, ss[ci][tl + 2*DIL], acc[ii])));
    }
  }
  float* op = y2p + (size_t)(b*C_ + co)*Y2S + 4 + tb + tq*16;
#pragma unroll
  for (int ii = 0; ii < 16; ii++) acc[ii] = lrelu_(acc[ii], 0.2f);
#pragma unroll
  for (int q = 0; q < 4; q++)
    *reinterpret_cast<float4*>(&op[q*4]) = make_float4(acc[q*4], acc[q*4+1], acc[q*4+2], acc[q*4+3]);
}

// ---------------------------------------------------------------- K7: DMA-pipelined MFMA KP-GEMM + LVC + gate + h update
// Block = (b, 64 frames, variant v). 8 waves = 4 frame-groups (fg) x 2 gate-halves (tp).
// tile = v + 2*tp (couts: sigmoid {v*16..+15}, tanh +32). EVERY wave runs the full
// 32-ci loop (576 MFMA) -> no ci reduction; epilogue = single gate-pair LDS exchange.
// Weights stream via double-buffered global_load_lds (12KB/step, 96 steps); loads are
// DMA so wave latency chains vanish (r4-r11 lesson: occupancy stuck at 1 block/CU,
// waves 80% stalled on per-lane weight loads).
#define NST 96
#define LOADY(SYR, TBASE)                                                        \
  {                                                                              \
    const float* yp = yr + (TBASE);                                              \
    float4 qa = *reinterpret_cast<const float4*>(yp - 4);                        \
    float4 qb = *reinterpret_cast<const float4*>(yp);                            \
    float4 qc = *reinterpret_cast<const float4*>(yp + 4);                        \
    float4 qd = *reinterpret_cast<const float4*>(yp + 8);                        \
    SYR[0] = qa.w;                                                               \
    SYR[1] = qb.x; SYR[2] = qb.y; SYR[3] = qb.z; SYR[4] = qb.w;                  \
    SYR[5] = qc.x; SYR[6] = qc.y; SYR[7] = qc.z; SYR[8] = qc.w;                  \
    SYR[9] = qd.x; SYR[10] = qd.y; SYR[11] = qd.z;                               \
  }

// stage STEP's weights (tiles v, v+2: 2 x 6KB contiguous chunks) into stg+BOFF
#define STAGE(BOFF, STEP)                                                        \
  {                                                                              \
    int rk4 = (layer*96 + (STEP))*4 + v;                                         \
    const unsigned short* gsrc = waf + (size_t)rk4*3072;                         \
    { int u = tid; int tpx = (u >= 384); int wi = u - tpx*384;                   \
      GLOAD16(gsrc + tpx*6144 + wi*8, (char*)stg + (BOFF) + u*16); }             \
    if (tid < 256) { int u = tid + 512; int wi = u - 384;                        \
      GLOAD16(gsrc + 6144 + wi*8, (char*)stg + (BOFF) + u*16); }                 \
  }

__global__ __launch_bounds__(512, 2) void k_lvc_mfma(
    const float* __restrict__ hkp, const unsigned short* __restrict__ waf,
    const float* __restrict__ kbt, const float* __restrict__ biasb,
    const float* __restrict__ y2p, const float* __restrict__ ad,
    float* __restrict__ h, int layer) {
  int b  = blockIdx.x >> 6;               // grid = B * 32 ftiles * 2 variants = 256
  int r6 = blockIdx.x & 63;
  int l0 = (r6 >> 1) * 64;                // 64 frames per block
  int v  = r6 & 1;

  // LDS pool, 58368 B total:
  //  [0,24576):    2 x 12KB weight stage buffers  (shh [64][66] lives here pre-loop)
  //  [24576,58368): red 4x64x33 f32 (epilogue)    (FB 24KB lives here pre-loop)
  __shared__ __align__(16) float pool[14592];
  float* shh = pool;                                        // [64][66]
  unsigned short* FB = (unsigned short*)(pool + 6144);      // 4 fg x 6 ks x 64 x 8
  float* red = pool + 6144;
  unsigned short* stg = (unsigned short*)pool;

  int tid = threadIdx.x;
  // Phase 1: hkp window (frames l0-1 .. l0+64)
  for (int idx = tid; idx < HID_*66; idx += 512) {
    int hh = idx / 66, j = idx % 66;
    int l = l0 - 1 + j;
    shh[hh*66 + j] = (l >= 0 && l < LMEL_) ? hkp[(b*HID_ + hh)*LMEL_ + l] : 0.f;
  }
  __syncthreads();
  // Phase 2: B fragments for 4 frame-groups
  for (int u = tid; u < 12288; u += 512) {
    int i = u & 7, lane2 = (u >> 3) & 63, ksf = u >> 9;     // ksf = fg*6 + ks
    int ks = ksf % 6, fg2 = ksf / 6;
    int k = ks*32 + ((lane2 >> 4) << 3) + i;
    int col = lane2 & 15;
    int hh = k / 3, q = k - hh*3;
    FB[u] = f2bf(shh[hh*66 + fg2*16 + col + q]);
  }
  __syncthreads();

  int wave = tid >> 6, lane = tid & 63;
  int tp = wave & 1, fg = wave >> 1;
  int tile = v + 2*tp;
  int f = lane & 15;

  v8s bfr[6];
#pragma unroll
  for (int ks = 0; ks < 6; ks++)
    bfr[ks] = *reinterpret_cast<const v8s*>(&FB[((fg*6 + ks)*64 + lane)*8]);

  float o[4][8];
#pragma unroll
  for (int r = 0; r < 4; r++)
#pragma unroll
    for (int s = 0; s < 8; s++) o[r][s] = 0.f;

  const float* ybase = y2p + ((size_t)(b*C_))*Y2S + 4;
  const int t0 = (l0 + fg*16 + f)*8;
  const int kbl = ((lane >> 4) << 2);

  STAGE(0, 0)
  __syncthreads();                         // stage 0 resident (barrier drains vmcnt)
  int cur = 0, step = 0;

  for (int ci = 0; ci < 32; ci++) {
    const float* yr = ybase + (size_t)ci*Y2S;
    float syr[12];
    LOADY(syr, t0)
#pragma unroll
    for (int kk = 0; kk < 3; kk++) {
      if (step < NST-1) STAGE((cur^1)*12288, step+1)       // DMA next while computing
      const unsigned short* sa = stg + cur*6144 + tp*3072;  // shorts
      v4f acc = {0.f, 0.f, 0.f, 0.f};
#pragma unroll
      for (int ks = 0; ks < 6; ks++) {
        v8s a = *reinterpret_cast<const v8s*>(sa + ks*512 + lane*8);
        acc = __builtin_amdgcn_mfma_f32_16x16x32_bf16(a, bfr[ks], acc, 0, 0, 0);
      }
      float4 kb4 = *reinterpret_cast<const float4*>(
          kbt + ((layer*96 + step)*4 + tile)*16 + kbl);
#pragma unroll
      for (int r = 0; r < 4; r++) {
        float kern = acc[r] + ((const float*)&kb4)[r];
#pragma unroll
        for (int s = 0; s < 8; s++)
          o[r][s] = fmaf(kern, syr[kk + s], o[r][s]);
      }
      __syncthreads();                     // next stage resident; cur buffer reusable
      cur ^= 1; step++;
    }
  }

  // epilogue: add bias, exchange tanh half, gate, h update (one barrier)
#pragma unroll
  for (int r = 0; r < 4; r++) {
    int cout = tile*16 + kbl + r;
    float bv = biasb[((size_t)b*BCH_ + layer*2*C_ + cout)*LMEL_ + l0 + fg*16 + f];
#pragma unroll
    for (int s = 0; s < 8; s++) o[r][s] += bv;
  }
  if (tp == 1) {
#pragma unroll
    for (int r = 0; r < 4; r++)
#pragma unroll
      for (int s = 0; s < 8; s++)
        red[(fg*64 + lane)*33 + r*8 + s] = o[r][s];
  }
  __syncthreads();
  if (tp == 0) {
#pragma unroll
    for (int r = 0; r < 4; r++) {
      int cout = v*16 + kbl + r;
      size_t base = ((size_t)b*C_ + cout)*LAUD_ + (size_t)(l0 + fg*16 + f)*HOP_;
      float4 h0 = *reinterpret_cast<const float4*>(&h[base]);
      float4 h1 = *reinterpret_cast<const float4*>(&h[base + 4]);
      float4 a0 = *reinterpret_cast<const float4*>(&ad[base]);
      float4 a1 = *reinterpret_cast<const float4*>(&ad[base + 4]);
      float outv[8];
#pragma unroll
      for (int s = 0; s < 8; s++) {
        float vv = o[r][s];
        float tv = red[(fg*64 + lane)*33 + r*8 + s];
        float sig = 1.f / (1.f + __expf(-vv));
        float th  = 1.f - 2.f / (1.f + __expf(2.f*tv));
        float hv = (s < 4) ? ((const float*)&h0)[s] : ((const float*)&h1)[s-4];
        float av = (s < 4) ? ((const float*)&a0)[s] : ((const float*)&a1)[s-4];
        outv[s] = hv + av + sig * th;
      }
      *reinterpret_cast<float4*>(&h[base])     = make_float4(outv[0], outv[1], outv[2], outv[3]);
      *reinterpret_cast<float4*>(&h[base + 4]) = make_float4(outv[4], outv[5], outv[6], outv[7]);
    }
  }
}

// ---------------------------------------------------------------- launcher
extern "C" void kernel_launch(void* const* d_in, const int* in_sizes, int n_in,
                              void* d_out, int out_size, void* d_ws, size_t ws_size,
                              hipStream_t stream) {
  const float* x     = (const float*)d_in[0];
  const float* ad    = (const float*)d_in[1];
  const float* c     = (const float*)d_in[2];
  const float* ne    = (const float*)d_in[3];
  const float* fw    = (const float*)d_in[4];
  const float* fb    = (const float*)d_in[5];
  const float* upw   = (const float*)d_in[6];
  const float* convw = (const float*)d_in[7];
  const float* kinw  = (const float*)d_in[8];
  const float* kinb  = (const float*)d_in[9];
  const float* krw1  = (const float*)d_in[10];
  const float* krb1  = (const float*)d_in[11];
  const float* krw2  = (const float*)d_in[12];
  const float* krb2  = (const float*)d_in[13];
  const float* kkw   = (const float*)d_in[14];
  const float* kkb   = (const float*)d_in[15];
  const float* kbw   = (const float*)d_in[16];
  const float* kbb   = (const float*)d_in[17];
  float* h = (float*)d_out;

  float* ws = (float*)d_ws;
  float* cond   = ws; ws += B_*COND_*LMEL_;
  float* hkpa   = ws; ws += B_*HID_*LMEL_;
  float* hkpb   = ws; ws += B_*HID_*LMEL_;
  float* biasb  = ws; ws += B_*BCH_*LMEL_;
  float* y2p    = ws; ws += B_*C_*Y2S;
  float* kbt    = ws; ws += KCH_;
  float* wtup   = ws; ws += C_*C_*16;
  float* kinwT  = ws; ws += HID_*COND_*5;
  float* krw1T  = ws; ws += 3*HID_*HID_*3;
  float* krw2T  = ws; ws += 3*HID_*HID_*3;
  float* kbwT   = ws; ws += BCH_*HID_*3;
  float* convwT = ws; ws += LAYERS_*C_*C_*3;
  unsigned short* waf = (unsigned short*)ws; ws += (KCH_*HID_*KPK_)/2;

  k_mkA<<<(KCH_*HID_*KPK_ + 255)/256, 256, 0, stream>>>(kkw, waf);
  k_mkKbT<<<(KCH_ + 255)/256, 256, 0, stream>>>(kkb, kbt);
  k_mkUp<<<(C_*C_*16 + 255)/256, 256, 0, stream>>>(upw, wtup);
  k_mkWTs<<<(HID_*COND_*5 + 255)/256, 256, 0, stream>>>(kinw, kinwT, 1, HID_, COND_*5);
  k_mkWTs<<<(3*HID_*HID_*3 + 255)/256, 256, 0, stream>>>(krw1, krw1T, 3, HID_, HID_*3);
  k_mkWTs<<<(3*HID_*HID_*3 + 255)/256, 256, 0, stream>>>(krw2, krw2T, 3, HID_, HID_*3);
  k_mkWTs<<<(BCH_*HID_*3 + 255)/256, 256, 0, stream>>>(kbw, kbwT, 1, BCH_, HID_*3);
  k_mkWTs<<<(LAYERS_*C_*C_*3 + 255)/256, 256, 0, stream>>>(convw, convwT, LAYERS_, C_, C_*3);

  k_noise_cond<<<B_*COND_, 256, 0, stream>>>(ne, fw, fb, c, cond);
  k_kp_in<<<B_*(LMEL_/32), 256, 0, stream>>>(cond, kinwT, kinb, hkpa);
  // res chain: a -> b -> a -> b  (final in hkpb)
  k_kp_res2<<<B_*(LMEL_/32), 256, 0, stream>>>(hkpa, krw1T + 0*HID_*HID_*3, krb1 + 0*HID_,
                                               krw2T + 0*HID_*HID_*3, krb2 + 0*HID_, hkpb);
  k_kp_res2<<<B_*(LMEL_/32), 256, 0, stream>>>(hkpb, krw1T + 1*HID_*HID_*3, krb1 + 1*HID_,
                                               krw2T + 1*HID_*HID_*3, krb2 + 1*HID_, hkpa);
  k_kp_res2<<<B_*(LMEL_/32), 256, 0, stream>>>(hkpa, krw1T + 2*HID_*HID_*3, krb1 + 2*HID_,
                                               krw2T + 2*HID_*HID_*3, krb2 + 2*HID_, hkpb);
  k_kp_bias<<<B_*(LMEL_/16), 256, 0, stream>>>(hkpb, kbwT, kbb, biasb);
  k_upsample<<<B_*65, 256, 0, stream>>>(x, wtup, h);

  for (int i = 0; i < LAYERS_; i++) {
    const float* wci = convwT + i*C_*C_*3;
    switch (i) {
      case 0: k_dilconv<1 ><<<B_*(LAUD_/128), 256, 0, stream>>>(h, ad, wci, y2p); break;
      case 1: k_dilconv<3 ><<<B_*(LAUD_/128), 256, 0, stream>>>(h, ad, wci, y2p); break;
      case 2: k_dilconv<9 ><<<B_*(LAUD_/128), 256, 0, stream>>>(h, ad, wci, y2p); break;
      case 3: k_dilconv<27><<<B_*(LAUD_/128), 256, 0, stream>>>(h, ad, wci, y2p); break;
    }
    k_lvc_mfma<<<B_*64, 512, 0, stream>>>(hkpb, waf, kbt, biasb, y2p, ad, h, i);
  }
}

// Round 13
// 502.560 us; speedup vs baseline: 1.3788x; 1.0628x over previous
//
#include <hip/hip_runtime.h>
#include <math.h>

#define B_      4
#define C_      32
#define COND_   80
#define LMEL_   2048
#define HOP_    8
#define UP_     8
#define LAYERS_ 4
#define K_      3
#define HID_    64
#define KPK_    3
#define EMB_    512
#define LAUD_   (LMEL_*UP_)          // 16384
#define KCH_    (LAYERS_*C_*2*C_*K_) // 24576
#define BCH_    (LAYERS_*2*C_)       // 256
#define Y2S     (LAUD_ + 8)          // padded y2 row stride (+4 each side)

typedef short v8s __attribute__((ext_vector_type(8)));
typedef float v4f __attribute__((ext_vector_type(4)));

__device__ __forceinline__ float lrelu_(float v, float s) { return v >= 0.f ? v : s * v; }

__device__ __forceinline__ unsigned short f2bf(float f) {  // RNE float->bf16
  unsigned int x = __float_as_uint(f);
  unsigned int r = (x + 0x7FFFu + ((x >> 16) & 1u)) >> 16;
  return (unsigned short)r;
}

// async global->LDS DMA, 16B per lane (guide §5: dest = wave-uniform base + lane*16)
#define GLOAD16(GSRC, LDST)                                              \
  __builtin_amdgcn_global_load_lds(                                     \
      (const __attribute__((address_space(1))) unsigned int*)(GSRC),    \
      (__attribute__((address_space(3))) unsigned int*)(LDST), 16, 0, 0)

#define WAITV(N) asm volatile("s_waitcnt vmcnt(" #N ")" ::: "memory")

// ---------------------------------------------------------------- prep: generic slab transpose src[s][oc][ick] -> dst[s][ick][oc]
__global__ void k_mkWTs(const float* __restrict__ src, float* __restrict__ dst,
                        int S, int OC, int ICK) {
  int idx = blockIdx.x*256 + threadIdx.x;
  if (idx >= S*OC*ICK) return;
  int s = idx / (OC*ICK), rem = idx % (OC*ICK);
  int oc = rem / ICK, ick = rem % ICK;
  dst[s*OC*ICK + ick*OC + oc] = src[idx];
}

// ---------------------------------------------------------------- K1: noise + condition
__global__ void k_noise_cond(const float* __restrict__ ne, const float* __restrict__ fw,
                             const float* __restrict__ fb, const float* __restrict__ c,
                             float* __restrict__ cond) {
  int b = blockIdx.x / COND_;
  int cc = blockIdx.x % COND_;
  __shared__ float red[256];
  float p = 0.f;
  for (int j = threadIdx.x; j < EMB_; j += 256)
    p += ne[b*EMB_ + j] * fw[cc*EMB_ + j];
  red[threadIdx.x] = p;
  __syncthreads();
  for (int s = 128; s > 0; s >>= 1) {
    if (threadIdx.x < s) red[threadIdx.x] += red[threadIdx.x + s];
    __syncthreads();
  }
  float noise = red[0] + fb[cc];
  const float* cp = c + (b*COND_ + cc)*LMEL_;
  float* op = cond + (b*COND_ + cc)*LMEL_;
  for (int l = threadIdx.x; l < LMEL_; l += 256) op[l] = cp[l] + noise;
}

// ---------------------------------------------------------------- K2: KP input conv (80->64, k=5, pad=2, lrelu 0.1), T=32, wT[(cc*5+k)*64+ch]
__global__ __launch_bounds__(256) void k_kp_in(const float* __restrict__ cond, const float* __restrict__ wT,
                                               const float* __restrict__ bias, float* __restrict__ out) {
  const int T = 32;
  int b  = blockIdx.x / (LMEL_/T);
  int lb = (blockIdx.x % (LMEL_/T)) * T;
  __shared__ float sc[COND_][T + 4];
  for (int idx = threadIdx.x; idx < COND_*(T+4); idx += 256) {
    int cc = idx / (T+4), j = idx % (T+4);
    int l = lb + j - 2;
    sc[cc][j] = (l >= 0 && l < LMEL_) ? cond[(b*COND_ + cc)*LMEL_ + l] : 0.f;
  }
  __syncthreads();
  int ch = threadIdx.x & 63;
  int lq = threadIdx.x >> 6;  // 0..3, 8 l's each
  float acc[8];
#pragma unroll
  for (int ii = 0; ii < 8; ii++) acc[ii] = bias[ch];
  for (int cc = 0; cc < COND_; cc++) {
    float r[12];
#pragma unroll
    for (int j = 0; j < 12; j++) r[j] = sc[cc][lq*8 + j];
#pragma unroll
    for (int k = 0; k < 5; k++) {
      float wv = wT[(cc*5 + k)*64 + ch];
#pragma unroll
      for (int ii = 0; ii < 8; ii++) acc[ii] = fmaf(wv, r[ii + k], acc[ii]);
    }
  }
  float* op = out + (b*HID_ + ch)*LMEL_ + lb + lq*8;
#pragma unroll
  for (int ii = 0; ii < 8; ii++) acc[ii] = lrelu_(acc[ii], 0.1f);
  *reinterpret_cast<float4*>(&op[0]) = make_float4(acc[0], acc[1], acc[2], acc[3]);
  *reinterpret_cast<float4*>(&op[4]) = make_float4(acc[4], acc[5], acc[6], acc[7]);
}

// ---------------------------------------------------------------- K3: fused res pair: out = in + lrelu(conv2(lrelu(conv1(in))))
__global__ __launch_bounds__(256) void k_kp_res2(const float* __restrict__ in,
                                                 const float* __restrict__ w1T, const float* __restrict__ b1,
                                                 const float* __restrict__ w2T, const float* __restrict__ b2,
                                                 float* __restrict__ out) {
  const int T = 32;
  int b  = blockIdx.x / (LMEL_/T);
  int lb = (blockIdx.x % (LMEL_/T)) * T;
  __shared__ float si[HID_][38];   // cols lb-2 .. lb+33 (36 used)
  __shared__ float sr[HID_][38];   // intermediate r, cols lb-1 .. lb+32 (34 used)
  for (int idx = threadIdx.x; idx < HID_*36; idx += 256) {
    int cc = idx / 36, j = idx % 36;
    int l = lb - 2 + j;
    si[cc][j] = (l >= 0 && l < LMEL_) ? in[(b*HID_ + cc)*LMEL_ + l] : 0.f;
  }
  __syncthreads();
  int ch = threadIdx.x & 63;
  int lq = threadIdx.x >> 6;   // 0..3
  {
    float b1v = b1[ch];
    float a1[9];
#pragma unroll
    for (int jj = 0; jj < 9; jj++) a1[jj] = b1v;
    for (int cc = 0; cc < HID_; cc++) {
      float r[11];
#pragma unroll
      for (int j = 0; j < 11; j++) r[j] = si[cc][lq*9 + j];
#pragma unroll
      for (int k = 0; k < 3; k++) {
        float wv = w1T[(cc*3 + k)*64 + ch];
#pragma unroll
        for (int jj = 0; jj < 9; jj++) a1[jj] = fmaf(wv, r[jj + k], a1[jj]);
      }
    }
#pragma unroll
    for (int jj = 0; jj < 9; jj++) {
      int m = lq*9 + jj;
      if (m < 34) sr[ch][m] = lrelu_(a1[jj], 0.1f);
    }
  }
  __syncthreads();
  {
    float b2v = b2[ch];
    float a2[8];
#pragma unroll
    for (int jj = 0; jj < 8; jj++) a2[jj] = b2v;
    for (int cc = 0; cc < HID_; cc++) {
      float r[10];
#pragma unroll
      for (int j = 0; j < 10; j++) r[j] = sr[cc][lq*8 + j];
#pragma unroll
      for (int k = 0; k < 3; k++) {
        float wv = w2T[(cc*3 + k)*64 + ch];
#pragma unroll
        for (int jj = 0; jj < 8; jj++) a2[jj] = fmaf(wv, r[jj + k], a2[jj]);
      }
    }
    float* op = out + (b*HID_ + ch)*LMEL_ + lb + lq*8;
    float v[8];
#pragma unroll
    for (int jj = 0; jj < 8; jj++)
      v[jj] = si[ch][lq*8 + jj + 2] + lrelu_(a2[jj], 0.1f);
    *reinterpret_cast<float4*>(&op[0]) = make_float4(v[0], v[1], v[2], v[3]);
    *reinterpret_cast<float4*>(&op[4]) = make_float4(v[4], v[5], v[6], v[7]);
  }
}

// ---------------------------------------------------------------- K4: bias conv (64->256, k=3, pad=1), T=16, wT[(cc*3+k)*256+ch]
__global__ __launch_bounds__(256) void k_kp_bias(const float* __restrict__ in, const float* __restrict__ wT,
                                                 const float* __restrict__ bias, float* __restrict__ out) {
  const int T = 16;
  int b  = blockIdx.x / (LMEL_/T);
  int lb = (blockIdx.x % (LMEL_/T)) * T;
  __shared__ float si[HID_][T + 2];
  for (int idx = threadIdx.x; idx < HID_*(T+2); idx += 256) {
    int cc = idx / (T+2), j = idx % (T+2);
    int l = lb + j - 1;
    si[cc][j] = (l >= 0 && l < LMEL_) ? in[(b*HID_ + cc)*LMEL_ + l] : 0.f;
  }
  __syncthreads();
  int ch = threadIdx.x;  // 0..255
  float acc[T];
  float bv = bias[ch];
#pragma unroll
  for (int ii = 0; ii < T; ii++) acc[ii] = bv;
  for (int cc = 0; cc < HID_; cc++) {
    float w0 = wT[(cc*3 + 0)*256 + ch];
    float w1 = wT[(cc*3 + 1)*256 + ch];
    float w2 = wT[(cc*3 + 2)*256 + ch];
#pragma unroll
    for (int ii = 0; ii < T; ii++)
      acc[ii] = fmaf(w0, si[cc][ii], fmaf(w1, si[cc][ii+1], fmaf(w2, si[cc][ii+2], acc[ii])));
  }
  float* op = out + (b*BCH_ + ch)*LMEL_ + lb;
#pragma unroll
  for (int q = 0; q < 4; q++)
    *reinterpret_cast<float4*>(&op[q*4]) = make_float4(acc[q*4], acc[q*4+1], acc[q*4+2], acc[q*4+3]);
}

// ---------------------------------------------------------------- prep: upsample weight transpose -> wt[(ci*16+j)*32+co]
__global__ void k_mkUp(const float* __restrict__ upw, float* __restrict__ wt) {
  int idx = blockIdx.x*256 + threadIdx.x;
  if (idx >= C_*C_*16) return;
  int co = idx & 31, j = (idx >> 5) & 15, ci = idx >> 9;
  wt[idx] = upw[(ci*C_ + co)*16 + j];
}

// ---------------------------------------------------------------- K5: upsample (conv_transpose1d stride 8, k=16, pad=4), lrelu(x,0.2) input
#define UT 32
__global__ __launch_bounds__(256) void k_upsample(const float* __restrict__ x, const float* __restrict__ wt,
                                                  float* __restrict__ h) {
  int b  = blockIdx.x / 65;
  int s0 = (blockIdx.x % 65) * UT;
  __shared__ float sw[16384];          // [ci][j][co]
  __shared__ float sx[C_][33 + 3];
  for (int idx = threadIdx.x*4; idx < 16384; idx += 1024)
    *reinterpret_cast<float4*>(&sw[idx]) = *reinterpret_cast<const float4*>(&wt[idx]);
  for (int idx = threadIdx.x; idx < C_*33; idx += 256) {
    int ci = idx / 33, i = idx % 33;
    int s = s0 - 1 + i;
    float v = (s >= 0 && s < LMEL_) ? x[(b*C_ + ci)*LMEL_ + s] : 0.f;
    sx[ci][i] = lrelu_(v, 0.2f);
  }
  __syncthreads();
  int co = threadIdx.x & 31, sq = threadIdx.x >> 5;  // sq 0..7, 4 frames each
  float acc[4][8];
#pragma unroll
  for (int k = 0; k < 4; k++)
#pragma unroll
    for (int r = 0; r < 8; r++) acc[k][r] = 0.f;
  for (int ci = 0; ci < C_; ci++) {
    float xv[5];
#pragma unroll
    for (int m = 0; m < 5; m++) xv[m] = sx[ci][sq*4 + m];
    const float* wl = &sw[ci*512 + co];
#pragma unroll
    for (int r = 0; r < 8; r++) {
      float wa = wl[r*32];
      float wb = wl[(r+8)*32];
#pragma unroll
      for (int k = 0; k < 4; k++)
        acc[k][r] = fmaf(wa, xv[k+1], fmaf(wb, xv[k], acc[k][r]));
    }
  }
  float* op = h + ((size_t)b*C_ + co)*LAUD_;
#pragma unroll
  for (int k = 0; k < 4; k++) {
    int s1 = s0 + sq*4 + k;
    int lo = 8*s1 - 4;
    if (lo >= 0 && lo + 4 <= LAUD_)
      *reinterpret_cast<float4*>(&op[lo]) = make_float4(acc[k][0], acc[k][1], acc[k][2], acc[k][3]);
    if (lo >= -4 && lo + 8 <= LAUD_)
      *reinterpret_cast<float4*>(&op[lo+4]) = make_float4(acc[k][4], acc[k][5], acc[k][6], acc[k][7]);
  }
}

// ---------------------------------------------------------------- prep: A-fragment-ordered bf16 weights
__global__ void k_mkA(const float* __restrict__ kw, unsigned short* __restrict__ waf) {
  int idx = blockIdx.x*256 + threadIdx.x;
  if (idx >= KCH_*HID_*KPK_) return;   // 4,718,592
  int i    = idx & 7;
  int lane = (idx >> 3) & 63;
  int ks   = (idx >> 9) % 6;
  int tile = (idx / 3072) & 3;
  int rk   = idx / 12288;              // 0..383
  int layer = rk / 96, rem = rk % 96, ci = rem / 3, kk = rem % 3;
  int cout = tile*16 + (lane & 15);
  int j    = ks*32 + ((lane >> 4) << 3) + i;
  int row  = ((layer*32 + ci)*64 + cout)*3 + kk;
  waf[idx] = f2bf(kw[row*192 + j]);
}

// ---------------------------------------------------------------- prep: kernel-conv bias reordered
__global__ void k_mkKbT(const float* __restrict__ kb, float* __restrict__ kbt) {
  int idx = blockIdx.x*256 + threadIdx.x;
  if (idx >= KCH_) return;             // 24576
  int cr = idx & 15, tile = (idx >> 4) & 3, rk = idx >> 6;
  int layer = rk / 96, rem = rk % 96, ci = rem / 3, kk = rem % 3;
  int cout = tile*16 + cr;
  kbt[idx] = kb[((layer*32 + ci)*64 + cout)*3 + kk];
}

// ---------------------------------------------------------------- K6: dilated conv (32->32, k=3) on lrelu(h+ad,0.2), out lrelu 0.2, T=128
template<int DIL>
__global__ __launch_bounds__(256) void k_dilconv(const float* __restrict__ h, const float* __restrict__ ad,
                                                 const float* __restrict__ wT, float* __restrict__ y2p) {
  const int T = 128;
  int b  = blockIdx.x / (LAUD_/T);
  int tb = (blockIdx.x % (LAUD_/T)) * T;
  const int W = T + 2*DIL;
  __shared__ float ss[C_][T + 2*27 + 4];
  for (int idx = threadIdx.x; idx < C_*W; idx += 256) {
    int ci = idx / W, j = idx % W;
    int t = tb - DIL + j;
    float v = 0.f;
    if (t >= 0 && t < LAUD_) {
      int g = (b*C_ + ci)*LAUD_ + t;
      v = h[g] + ad[g];
    }
    ss[ci][j] = lrelu_(v, 0.2f);
  }
  // zero y2 pads
  if (tb == 0 && threadIdx.x < 128) {
    int ci = threadIdx.x >> 2, q = threadIdx.x & 3;
    y2p[(size_t)(b*C_ + ci)*Y2S + q] = 0.f;
  }
  if (tb == LAUD_ - T && threadIdx.x < 128) {
    int ci = threadIdx.x >> 2, q = threadIdx.x & 3;
    y2p[(size_t)(b*C_ + ci)*Y2S + 4 + LAUD_ + q] = 0.f;
  }
  __syncthreads();
  int co = threadIdx.x & 31, tq = threadIdx.x >> 5;
  float acc[16];
#pragma unroll
  for (int ii = 0; ii < 16; ii++) acc[ii] = 0.f;
  for (int ci = 0; ci < C_; ci++) {
    float w0 = wT[(ci*3 + 0)*32 + co];
    float w1 = wT[(ci*3 + 1)*32 + co];
    float w2 = wT[(ci*3 + 2)*32 + co];
#pragma unroll
    for (int ii = 0; ii < 16; ii++) {
      int tl = tq*16 + ii;
      acc[ii] = fmaf(w0, ss[ci][tl], fmaf(w1, ss[ci][tl + DIL], fmaf(w2, ss[ci][tl + 2*DIL], acc[ii])));
    }
  }
  float* op = y2p + (size_t)(b*C_ + co)*Y2S + 4 + tb + tq*16;
#pragma unroll
  for (int ii = 0; ii < 16; ii++) acc[ii] = lrelu_(acc[ii], 0.2f);
#pragma unroll
  for (int q = 0; q < 4; q++)
    *reinterpret_cast<float4*>(&op[q*4]) = make_float4(acc[q*4], acc[q*4+1], acc[q*4+2], acc[q*4+3]);
}

// ---------------------------------------------------------------- K7: counted-vmcnt DMA-pipelined MFMA KP-GEMM + LVC + gate + h update
// Block = (b, 64 frames, variant v). 8 waves = 4 frame-groups (fg) x 2 gate-halves (tp).
// Loop body VMEM = ONLY global_load_lds chunks (y2/kbt pre-staged in LDS) -> exact
// per-wave vmcnt counting. 4-deep 12KB ring; iter i: issue chunk(i+2), waitcnt keeps
// the newest chunk in flight (never vmcnt(0) in-loop, T4), raw s_barrier.
// LDS map (152064 B total):
//   [0,49152)        stg ring 4 x 12288   (aliased pre-loop by shh, post-loop by red)
//   [49152,73728)    FB  B-fragments (4 fg x 6 ks x 64 x 8 bf16)
//   [73728,86016)    kbt_s (96 steps x 2 tp x 16 f32)
//   [86016,152064)   sy   (32 ci x 516 f32, samples l0*8-1 .. +513 from padded y2p)
#define STAGE(BUF, STEP)                                                         \
  {                                                                              \
    const unsigned short* gsrc = waf + (size_t)((layer*96 + (STEP))*4)*3072;     \
    { int u = tid; int tpx = (u >= 384); int wi = u - tpx*384;                   \
      GLOAD16(gsrc + (v + 2*tpx)*3072 + wi*8,                                    \
              (char*)stg + (BUF)*12288 + u*16); }                                \
    if (tid < 256) { int u = tid + 512; int wi = u - 384;                        \
      GLOAD16(gsrc + (v + 2)*3072 + wi*8, (char*)stg + (BUF)*12288 + u*16); }    \
  }

__global__ __launch_bounds__(512, 2) void k_lvc_mfma(
    const float* __restrict__ hkp, const unsigned short* __restrict__ waf,
    const float* __restrict__ kbt, const float* __restrict__ biasb,
    const float* __restrict__ y2p, const float* __restrict__ ad,
    float* __restrict__ h, int layer) {
  int b  = blockIdx.x >> 6;               // grid = B * 32 ftiles * 2 variants = 256
  int r6 = blockIdx.x & 63;
  int l0 = (r6 >> 1) * 64;                // 64 frames per block
  int v  = r6 & 1;

  __shared__ __align__(16) char pool[152064];
  unsigned short* stg   = (unsigned short*)pool;                  // ring, 49152 B
  unsigned short* FB    = (unsigned short*)(pool + 49152);        // 24576 B
  float*          kbt_s = (float*)(pool + 73728);                 // 12288 B
  float*          sy    = (float*)(pool + 86016);                 // 66048 B
  float*          shh   = (float*)pool;                           // pre-loop alias
  float*          red   = (float*)pool;                           // post-loop alias

  int tid = threadIdx.x;
  // Phase 1a: sy stage — padded y2p means no bounds checks (t in [-1, LAUD+2])
  {
    const float* ysrc = y2p + (size_t)(b*C_)*Y2S + 4 + (size_t)l0*8 - 1;
    for (int idx = tid; idx < 32*514; idx += 512) {
      int ci = idx / 514, j = idx % 514;
      sy[ci*516 + j] = ysrc[(size_t)ci*Y2S + j];
    }
  }
  // Phase 1b: kbt stage
  for (int u = tid; u < 3072; u += 512) {
    int step = u >> 5, tp2 = (u >> 4) & 1, cr = u & 15;
    kbt_s[u] = kbt[((layer*96 + step)*4 + v + 2*tp2)*16 + cr];
  }
  // Phase 1c: hkp window (frames l0-1 .. l0+64) into shh (aliases stg)
  for (int idx = tid; idx < HID_*66; idx += 512) {
    int hh = idx / 66, j = idx % 66;
    int l = l0 - 1 + j;
    shh[hh*66 + j] = (l >= 0 && l < LMEL_) ? hkp[(b*HID_ + hh)*LMEL_ + l] : 0.f;
  }
  __syncthreads();
  // Phase 2: B fragments for 4 frame-groups
  for (int u = tid; u < 12288; u += 512) {
    int i = u & 7, lane2 = (u >> 3) & 63, ksf = u >> 9;     // ksf = fg*6 + ks
    int ks = ksf % 6, fg2 = ksf / 6;
    int k = ks*32 + ((lane2 >> 4) << 3) + i;
    int col = lane2 & 15;
    int hh = k / 3, q = k - hh*3;
    FB[u] = f2bf(shh[hh*66 + fg2*16 + col + q]);
  }
  __syncthreads();

  int wave = tid >> 6, lane = tid & 63;
  int tp = wave & 1, fg = wave >> 1;
  int f = lane & 15;
  const int kbl = ((lane >> 4) << 2);

  v8s bfr[6];
#pragma unroll
  for (int ks = 0; ks < 6; ks++)
    bfr[ks] = *reinterpret_cast<const v8s*>(&FB[((fg*6 + ks)*64 + lane)*8]);

  float o[4][8];
#pragma unroll
  for (int r = 0; r < 4; r++)
#pragma unroll
    for (int s = 0; s < 8; s++) o[r][s] = 0.f;

  // prologue: chunks 0,1 in flight; wait own chunk-0 loads; barrier
  STAGE(0, 0)
  STAGE(1, 1)
  if (wave < 4) { WAITV(2); } else { WAITV(1); }
  __builtin_amdgcn_s_barrier();

  const int sybase = (fg*16 + f)*8;

  for (int ci = 0; ci < 32; ci++) {
    float syr[12];
    {
      const float* yrow = sy + ci*516 + sybase;
      float4 q0 = *reinterpret_cast<const float4*>(yrow);
      float4 q1 = *reinterpret_cast<const float4*>(yrow + 4);
      float4 q2 = *reinterpret_cast<const float4*>(yrow + 8);
      syr[0]=q0.x; syr[1]=q0.y; syr[2]=q0.z; syr[3]=q0.w;
      syr[4]=q1.x; syr[5]=q1.y; syr[6]=q1.z; syr[7]=q1.w;
      syr[8]=q2.x; syr[9]=q2.y; syr[10]=q2.z; syr[11]=q2.w;
    }
#pragma unroll
    for (int kk = 0; kk < 3; kk++) {
      int step = ci*3 + kk;
      // issue chunk(step+2), counted wait (keep newest chunk in flight), barrier
      if (step < 94) {
        STAGE((step + 2) & 3, step + 2)
        if (wave < 4) { WAITV(2); } else { WAITV(1); }
      } else {
        WAITV(0);
      }
      __builtin_amdgcn_s_barrier();

      const unsigned short* sa = stg + (step & 3)*6144 + tp*3072;
      v4f acc = {0.f, 0.f, 0.f, 0.f};
#pragma unroll
      for (int ks = 0; ks < 6; ks++) {
        v8s a = *reinterpret_cast<const v8s*>(sa + ks*512 + lane*8);
        acc = __builtin_amdgcn_mfma_f32_16x16x32_bf16(a, bfr[ks], acc, 0, 0, 0);
      }
      float4 kb4 = *reinterpret_cast<const float4*>(&kbt_s[(step*2 + tp)*16 + kbl]);
#pragma unroll
      for (int r = 0; r < 4; r++) {
        float kern = acc[r] + ((const float*)&kb4)[r];
#pragma unroll
        for (int s = 0; s < 8; s++)
          o[r][s] = fmaf(kern, syr[kk + s], o[r][s]);
      }
    }
  }

  // epilogue: bias, gate-pair exchange via red (aliases ring bufs 0-2; last compute
  // read buf3 -> disjoint), gate, h update
#pragma unroll
  for (int r = 0; r < 4; r++) {
    int cout = (v + 2*tp)*16 + kbl + r;
    float bv = biasb[((size_t)b*BCH_ + layer*2*C_ + cout)*LMEL_ + l0 + fg*16 + f];
#pragma unroll
    for (int s = 0; s < 8; s++) o[r][s] += bv;
  }
  if (tp == 1) {
#pragma unroll
    for (int r = 0; r < 4; r++)
#pragma unroll
      for (int s = 0; s < 8; s++)
        red[(fg*64 + lane)*33 + r*8 + s] = o[r][s];
  }
  __syncthreads();
  if (tp == 0) {
#pragma unroll
    for (int r = 0; r < 4; r++) {
      int cout = v*16 + kbl + r;
      size_t base = ((size_t)b*C_ + cout)*LAUD_ + (size_t)(l0 + fg*16 + f)*HOP_;
      float4 h0 = *reinterpret_cast<const float4*>(&h[base]);
      float4 h1 = *reinterpret_cast<const float4*>(&h[base + 4]);
      float4 a0 = *reinterpret_cast<const float4*>(&ad[base]);
      float4 a1 = *reinterpret_cast<const float4*>(&ad[base + 4]);
      float outv[8];
#pragma unroll
      for (int s = 0; s < 8; s++) {
        float vv = o[r][s];
        float tv = red[(fg*64 + lane)*33 + r*8 + s];
        float sig = 1.f / (1.f + __expf(-vv));
        float th  = 1.f - 2.f / (1.f + __expf(2.f*tv));
        float hv = (s < 4) ? ((const float*)&h0)[s] : ((const float*)&h1)[s-4];
        float av = (s < 4) ? ((const float*)&a0)[s] : ((const float*)&a1)[s-4];
        outv[s] = hv + av + sig * th;
      }
      *reinterpret_cast<float4*>(&h[base])     = make_float4(outv[0], outv[1], outv[2], outv[3]);
      *reinterpret_cast<float4*>(&h[base + 4]) = make_float4(outv[4], outv[5], outv[6], outv[7]);
    }
  }
}

// ---------------------------------------------------------------- launcher
extern "C" void kernel_launch(void* const* d_in, const int* in_sizes, int n_in,
                              void* d_out, int out_size, void* d_ws, size_t ws_size,
                              hipStream_t stream) {
  const float* x     = (const float*)d_in[0];
  const float* ad    = (const float*)d_in[1];
  const float* c     = (const float*)d_in[2];
  const float* ne    = (const float*)d_in[3];
  const float* fw    = (const float*)d_in[4];
  const float* fb    = (const float*)d_in[5];
  const float* upw   = (const float*)d_in[6];
  const float* convw = (const float*)d_in[7];
  const float* kinw  = (const float*)d_in[8];
  const float* kinb  = (const float*)d_in[9];
  const float* krw1  = (const float*)d_in[10];
  const float* krb1  = (const float*)d_in[11];
  const float* krw2  = (const float*)d_in[12];
  const float* krb2  = (const float*)d_in[13];
  const float* kkw   = (const float*)d_in[14];
  const float* kkb   = (const float*)d_in[15];
  const float* kbw   = (const float*)d_in[16];
  const float* kbb   = (const float*)d_in[17];
  float* h = (float*)d_out;

  float* ws = (float*)d_ws;
  float* cond   = ws; ws += B_*COND_*LMEL_;
  float* hkpa   = ws; ws += B_*HID_*LMEL_;
  float* hkpb   = ws; ws += B_*HID_*LMEL_;
  float* biasb  = ws; ws += B_*BCH_*LMEL_;
  float* y2p    = ws; ws += B_*C_*Y2S;
  float* kbt    = ws; ws += KCH_;
  float* wtup   = ws; ws += C_*C_*16;
  float* kinwT  = ws; ws += HID_*COND_*5;
  float* krw1T  = ws; ws += 3*HID_*HID_*3;
  float* krw2T  = ws; ws += 3*HID_*HID_*3;
  float* kbwT   = ws; ws += BCH_*HID_*3;
  float* convwT = ws; ws += LAYERS_*C_*C_*3;
  unsigned short* waf = (unsigned short*)ws; ws += (KCH_*HID_*KPK_)/2;

  k_mkA<<<(KCH_*HID_*KPK_ + 255)/256, 256, 0, stream>>>(kkw, waf);
  k_mkKbT<<<(KCH_ + 255)/256, 256, 0, stream>>>(kkb, kbt);
  k_mkUp<<<(C_*C_*16 + 255)/256, 256, 0, stream>>>(upw, wtup);
  k_mkWTs<<<(HID_*COND_*5 + 255)/256, 256, 0, stream>>>(kinw, kinwT, 1, HID_, COND_*5);
  k_mkWTs<<<(3*HID_*HID_*3 + 255)/256, 256, 0, stream>>>(krw1, krw1T, 3, HID_, HID_*3);
  k_mkWTs<<<(3*HID_*HID_*3 + 255)/256, 256, 0, stream>>>(krw2, krw2T, 3, HID_, HID_*3);
  k_mkWTs<<<(BCH_*HID_*3 + 255)/256, 256, 0, stream>>>(kbw, kbwT, 1, BCH_, HID_*3);
  k_mkWTs<<<(LAYERS_*C_*C_*3 + 255)/256, 256, 0, stream>>>(convw, convwT, LAYERS_, C_, C_*3);

  k_noise_cond<<<B_*COND_, 256, 0, stream>>>(ne, fw, fb, c, cond);
  k_kp_in<<<B_*(LMEL_/32), 256, 0, stream>>>(cond, kinwT, kinb, hkpa);
  // res chain: a -> b -> a -> b  (final in hkpb)
  k_kp_res2<<<B_*(LMEL_/32), 256, 0, stream>>>(hkpa, krw1T + 0*HID_*HID_*3, krb1 + 0*HID_,
                                               krw2T + 0*HID_*HID_*3, krb2 + 0*HID_, hkpb);
  k_kp_res2<<<B_*(LMEL_/32), 256, 0, stream>>>(hkpb, krw1T + 1*HID_*HID_*3, krb1 + 1*HID_,
                                               krw2T + 1*HID_*HID_*3, krb2 + 1*HID_, hkpa);
  k_kp_res2<<<B_*(LMEL_/32), 256, 0, stream>>>(hkpa, krw1T + 2*HID_*HID_*3, krb1 + 2*HID_,
                                               krw2T + 2*HID_*HID_*3, krb2 + 2*HID_, hkpb);
  k_kp_bias<<<B_*(LMEL_/16), 256, 0, stream>>>(hkpb, kbwT, kbb, biasb);
  k_upsample<<<B_*65, 256, 0, stream>>>(x, wtup, h);

  for (int i = 0; i < LAYERS_; i++) {
    const float* wci = convwT + i*C_*C_*3;
    switch (i) {
      case 0: k_dilconv<1 ><<<B_*(LAUD_/128), 256, 0, stream>>>(h, ad, wci, y2p); break;
      case 1: k_dilconv<3 ><<<B_*(LAUD_/128), 256, 0, stream>>>(h, ad, wci, y2p); break;
      case 2: k_dilconv<9 ><<<B_*(LAUD_/128), 256, 0, stream>>>(h, ad, wci, y2p); break;
      case 3: k_dilconv<27><<<B_*(LAUD_/128), 256, 0, stream>>>(h, ad, wci, y2p); break;
    }
    k_lvc_mfma<<<B_*64, 512, 0, stream>>>(hkpb, waf, kbt, biasb, y2p, ad, h, i);
  }
}

// Round 14
// 489.400 us; speedup vs baseline: 1.4159x; 1.0269x over previous
//
#include <hip/hip_runtime.h>
#include <math.h>

#define B_      4
#define C_      32
#define COND_   80
#define LMEL_   2048
#define HOP_    8
#define UP_     8
#define LAYERS_ 4
#define K_      3
#define HID_    64
#define KPK_    3
#define EMB_    512
#define LAUD_   (LMEL_*UP_)          // 16384
#define KCH_    (LAYERS_*C_*2*C_*K_) // 24576
#define BCH_    (LAYERS_*2*C_)       // 256
#define Y2S     (LAUD_ + 8)          // padded y2 row stride (+4 each side)

typedef short v8s __attribute__((ext_vector_type(8)));
typedef float v4f __attribute__((ext_vector_type(4)));

__device__ __forceinline__ float lrelu_(float v, float s) { return v >= 0.f ? v : s * v; }

__device__ __forceinline__ unsigned short f2bf(float f) {  // RNE float->bf16
  unsigned int x = __float_as_uint(f);
  unsigned int r = (x + 0x7FFFu + ((x >> 16) & 1u)) >> 16;
  return (unsigned short)r;
}

// async global->LDS DMA, 16B per lane (guide §5: dest = wave-uniform base + lane*16)
#define GLOAD16(GSRC, LDST)                                              \
  __builtin_amdgcn_global_load_lds(                                     \
      (const __attribute__((address_space(1))) unsigned int*)(GSRC),    \
      (__attribute__((address_space(3))) unsigned int*)(LDST), 16, 0, 0)

#define WAITV(N) asm volatile("s_waitcnt vmcnt(" #N ")" ::: "memory")

// ---------------------------------------------------------------- prep: generic slab transpose src[s][oc][ick] -> dst[s][ick][oc]
__global__ void k_mkWTs(const float* __restrict__ src, float* __restrict__ dst,
                        int S, int OC, int ICK) {
  int idx = blockIdx.x*256 + threadIdx.x;
  if (idx >= S*OC*ICK) return;
  int s = idx / (OC*ICK), rem = idx % (OC*ICK);
  int oc = rem / ICK, ick = rem % ICK;
  dst[s*OC*ICK + ick*OC + oc] = src[idx];
}

// ---------------------------------------------------------------- K1: noise + condition
__global__ void k_noise_cond(const float* __restrict__ ne, const float* __restrict__ fw,
                             const float* __restrict__ fb, const float* __restrict__ c,
                             float* __restrict__ cond) {
  int b = blockIdx.x / COND_;
  int cc = blockIdx.x % COND_;
  __shared__ float red[256];
  float p = 0.f;
  for (int j = threadIdx.x; j < EMB_; j += 256)
    p += ne[b*EMB_ + j] * fw[cc*EMB_ + j];
  red[threadIdx.x] = p;
  __syncthreads();
  for (int s = 128; s > 0; s >>= 1) {
    if (threadIdx.x < s) red[threadIdx.x] += red[threadIdx.x + s];
    __syncthreads();
  }
  float noise = red[0] + fb[cc];
  const float* cp = c + (b*COND_ + cc)*LMEL_;
  float* op = cond + (b*COND_ + cc)*LMEL_;
  for (int l = threadIdx.x; l < LMEL_; l += 256) op[l] = cp[l] + noise;
}

// ---------------------------------------------------------------- K2: KP input conv (80->64, k=5, pad=2, lrelu 0.1), T=32, wT[(cc*5+k)*64+ch]
__global__ __launch_bounds__(256) void k_kp_in(const float* __restrict__ cond, const float* __restrict__ wT,
                                               const float* __restrict__ bias, float* __restrict__ out) {
  const int T = 32;
  int b  = blockIdx.x / (LMEL_/T);
  int lb = (blockIdx.x % (LMEL_/T)) * T;
  __shared__ float sc[COND_][T + 4];
  for (int idx = threadIdx.x; idx < COND_*(T+4); idx += 256) {
    int cc = idx / (T+4), j = idx % (T+4);
    int l = lb + j - 2;
    sc[cc][j] = (l >= 0 && l < LMEL_) ? cond[(b*COND_ + cc)*LMEL_ + l] : 0.f;
  }
  __syncthreads();
  int ch = threadIdx.x & 63;
  int lq = threadIdx.x >> 6;  // 0..3, 8 l's each
  float acc[8];
#pragma unroll
  for (int ii = 0; ii < 8; ii++) acc[ii] = bias[ch];
  for (int cc = 0; cc < COND_; cc++) {
    float r[12];
#pragma unroll
    for (int j = 0; j < 12; j++) r[j] = sc[cc][lq*8 + j];
#pragma unroll
    for (int k = 0; k < 5; k++) {
      float wv = wT[(cc*5 + k)*64 + ch];
#pragma unroll
      for (int ii = 0; ii < 8; ii++) acc[ii] = fmaf(wv, r[ii + k], acc[ii]);
    }
  }
  float* op = out + (b*HID_ + ch)*LMEL_ + lb + lq*8;
#pragma unroll
  for (int ii = 0; ii < 8; ii++) acc[ii] = lrelu_(acc[ii], 0.1f);
  *reinterpret_cast<float4*>(&op[0]) = make_float4(acc[0], acc[1], acc[2], acc[3]);
  *reinterpret_cast<float4*>(&op[4]) = make_float4(acc[4], acc[5], acc[6], acc[7]);
}

// ---------------------------------------------------------------- K3: fused res pair: out = in + lrelu(conv2(lrelu(conv1(in))))
__global__ __launch_bounds__(256) void k_kp_res2(const float* __restrict__ in,
                                                 const float* __restrict__ w1T, const float* __restrict__ b1,
                                                 const float* __restrict__ w2T, const float* __restrict__ b2,
                                                 float* __restrict__ out) {
  const int T = 32;
  int b  = blockIdx.x / (LMEL_/T);
  int lb = (blockIdx.x % (LMEL_/T)) * T;
  __shared__ float si[HID_][38];   // cols lb-2 .. lb+33 (36 used)
  __shared__ float sr[HID_][38];   // intermediate r, cols lb-1 .. lb+32 (34 used)
  for (int idx = threadIdx.x; idx < HID_*36; idx += 256) {
    int cc = idx / 36, j = idx % 36;
    int l = lb - 2 + j;
    si[cc][j] = (l >= 0 && l < LMEL_) ? in[(b*HID_ + cc)*LMEL_ + l] : 0.f;
  }
  __syncthreads();
  int ch = threadIdx.x & 63;
  int lq = threadIdx.x >> 6;   // 0..3
  {
    float b1v = b1[ch];
    float a1[9];
#pragma unroll
    for (int jj = 0; jj < 9; jj++) a1[jj] = b1v;
    for (int cc = 0; cc < HID_; cc++) {
      float r[11];
#pragma unroll
      for (int j = 0; j < 11; j++) r[j] = si[cc][lq*9 + j];
#pragma unroll
      for (int k = 0; k < 3; k++) {
        float wv = w1T[(cc*3 + k)*64 + ch];
#pragma unroll
        for (int jj = 0; jj < 9; jj++) a1[jj] = fmaf(wv, r[jj + k], a1[jj]);
      }
    }
#pragma unroll
    for (int jj = 0; jj < 9; jj++) {
      int m = lq*9 + jj;
      if (m < 34) sr[ch][m] = lrelu_(a1[jj], 0.1f);
    }
  }
  __syncthreads();
  {
    float b2v = b2[ch];
    float a2[8];
#pragma unroll
    for (int jj = 0; jj < 8; jj++) a2[jj] = b2v;
    for (int cc = 0; cc < HID_; cc++) {
      float r[10];
#pragma unroll
      for (int j = 0; j < 10; j++) r[j] = sr[cc][lq*8 + j];
#pragma unroll
      for (int k = 0; k < 3; k++) {
        float wv = w2T[(cc*3 + k)*64 + ch];
#pragma unroll
        for (int jj = 0; jj < 8; jj++) a2[jj] = fmaf(wv, r[jj + k], a2[jj]);
      }
    }
    float* op = out + (b*HID_ + ch)*LMEL_ + lb + lq*8;
    float v[8];
#pragma unroll
    for (int jj = 0; jj < 8; jj++)
      v[jj] = si[ch][lq*8 + jj + 2] + lrelu_(a2[jj], 0.1f);
    *reinterpret_cast<float4*>(&op[0]) = make_float4(v[0], v[1], v[2], v[3]);
    *reinterpret_cast<float4*>(&op[4]) = make_float4(v[4], v[5], v[6], v[7]);
  }
}

// ---------------------------------------------------------------- K4: bias conv (64->256, k=3, pad=1), T=16, wT[(cc*3+k)*256+ch]
__global__ __launch_bounds__(256) void k_kp_bias(const float* __restrict__ in, const float* __restrict__ wT,
                                                 const float* __restrict__ bias, float* __restrict__ out) {
  const int T = 16;
  int b  = blockIdx.x / (LMEL_/T);
  int lb = (blockIdx.x % (LMEL_/T)) * T;
  __shared__ float si[HID_][T + 2];
  for (int idx = threadIdx.x; idx < HID_*(T+2); idx += 256) {
    int cc = idx / (T+2), j = idx % (T+2);
    int l = lb + j - 1;
    si[cc][j] = (l >= 0 && l < LMEL_) ? in[(b*HID_ + cc)*LMEL_ + l] : 0.f;
  }
  __syncthreads();
  int ch = threadIdx.x;  // 0..255
  float acc[T];
  float bv = bias[ch];
#pragma unroll
  for (int ii = 0; ii < T; ii++) acc[ii] = bv;
  for (int cc = 0; cc < HID_; cc++) {
    float w0 = wT[(cc*3 + 0)*256 + ch];
    float w1 = wT[(cc*3 + 1)*256 + ch];
    float w2 = wT[(cc*3 + 2)*256 + ch];
#pragma unroll
    for (int ii = 0; ii < T; ii++)
      acc[ii] = fmaf(w0, si[cc][ii], fmaf(w1, si[cc][ii+1], fmaf(w2, si[cc][ii+2], acc[ii])));
  }
  float* op = out + (b*BCH_ + ch)*LMEL_ + lb;
#pragma unroll
  for (int q = 0; q < 4; q++)
    *reinterpret_cast<float4*>(&op[q*4]) = make_float4(acc[q*4], acc[q*4+1], acc[q*4+2], acc[q*4+3]);
}

// ---------------------------------------------------------------- prep: upsample weight transpose -> wt[(ci*16+j)*32+co]
__global__ void k_mkUp(const float* __restrict__ upw, float* __restrict__ wt) {
  int idx = blockIdx.x*256 + threadIdx.x;
  if (idx >= C_*C_*16) return;
  int co = idx & 31, j = (idx >> 5) & 15, ci = idx >> 9;
  wt[idx] = upw[(ci*C_ + co)*16 + j];
}

// ---------------------------------------------------------------- K5: upsample (conv_transpose1d stride 8, k=16, pad=4), lrelu(x,0.2) input
#define UT 32
__global__ __launch_bounds__(256) void k_upsample(const float* __restrict__ x, const float* __restrict__ wt,
                                                  float* __restrict__ h) {
  int b  = blockIdx.x / 65;
  int s0 = (blockIdx.x % 65) * UT;
  __shared__ float sw[16384];          // [ci][j][co]
  __shared__ float sx[C_][33 + 3];
  for (int idx = threadIdx.x*4; idx < 16384; idx += 1024)
    *reinterpret_cast<float4*>(&sw[idx]) = *reinterpret_cast<const float4*>(&wt[idx]);
  for (int idx = threadIdx.x; idx < C_*33; idx += 256) {
    int ci = idx / 33, i = idx % 33;
    int s = s0 - 1 + i;
    float v = (s >= 0 && s < LMEL_) ? x[(b*C_ + ci)*LMEL_ + s] : 0.f;
    sx[ci][i] = lrelu_(v, 0.2f);
  }
  __syncthreads();
  int co = threadIdx.x & 31, sq = threadIdx.x >> 5;  // sq 0..7, 4 frames each
  float acc[4][8];
#pragma unroll
  for (int k = 0; k < 4; k++)
#pragma unroll
    for (int r = 0; r < 8; r++) acc[k][r] = 0.f;
  for (int ci = 0; ci < C_; ci++) {
    float xv[5];
#pragma unroll
    for (int m = 0; m < 5; m++) xv[m] = sx[ci][sq*4 + m];
    const float* wl = &sw[ci*512 + co];
#pragma unroll
    for (int r = 0; r < 8; r++) {
      float wa = wl[r*32];
      float wb = wl[(r+8)*32];
#pragma unroll
      for (int k = 0; k < 4; k++)
        acc[k][r] = fmaf(wa, xv[k+1], fmaf(wb, xv[k], acc[k][r]));
    }
  }
  float* op = h + ((size_t)b*C_ + co)*LAUD_;
#pragma unroll
  for (int k = 0; k < 4; k++) {
    int s1 = s0 + sq*4 + k;
    int lo = 8*s1 - 4;
    if (lo >= 0 && lo + 4 <= LAUD_)
      *reinterpret_cast<float4*>(&op[lo]) = make_float4(acc[k][0], acc[k][1], acc[k][2], acc[k][3]);
    if (lo >= -4 && lo + 8 <= LAUD_)
      *reinterpret_cast<float4*>(&op[lo+4]) = make_float4(acc[k][4], acc[k][5], acc[k][6], acc[k][7]);
  }
}

// ---------------------------------------------------------------- prep: A-fragment-ordered bf16 weights
__global__ void k_mkA(const float* __restrict__ kw, unsigned short* __restrict__ waf) {
  int idx = blockIdx.x*256 + threadIdx.x;
  if (idx >= KCH_*HID_*KPK_) return;   // 4,718,592
  int i    = idx & 7;
  int lane = (idx >> 3) & 63;
  int ks   = (idx >> 9) % 6;
  int tile = (idx / 3072) & 3;
  int rk   = idx / 12288;              // 0..383
  int layer = rk / 96, rem = rk % 96, ci = rem / 3, kk = rem % 3;
  int cout = tile*16 + (lane & 15);
  int j    = ks*32 + ((lane >> 4) << 3) + i;
  int row  = ((layer*32 + ci)*64 + cout)*3 + kk;
  waf[idx] = f2bf(kw[row*192 + j]);
}

// ---------------------------------------------------------------- prep: kernel-conv bias reordered
__global__ void k_mkKbT(const float* __restrict__ kb, float* __restrict__ kbt) {
  int idx = blockIdx.x*256 + threadIdx.x;
  if (idx >= KCH_) return;             // 24576
  int cr = idx & 15, tile = (idx >> 4) & 3, rk = idx >> 6;
  int layer = rk / 96, rem = rk % 96, ci = rem / 3, kk = rem % 3;
  int cout = tile*16 + cr;
  kbt[idx] = kb[((layer*32 + ci)*64 + cout)*3 + kk];
}

// ---------------------------------------------------------------- K6: dilated conv (32->32, k=3) on lrelu(h+ad,0.2), out lrelu 0.2, T=128
template<int DIL>
__global__ __launch_bounds__(256) void k_dilconv(const float* __restrict__ h, const float* __restrict__ ad,
                                                 const float* __restrict__ wT, float* __restrict__ y2p) {
  const int T = 128;
  int b  = blockIdx.x / (LAUD_/T);
  int tb = (blockIdx.x % (LAUD_/T)) * T;
  const int W = T + 2*DIL;
  __shared__ float ss[C_][T + 2*27 + 4];
  for (int idx = threadIdx.x; idx < C_*W; idx += 256) {
    int ci = idx / W, j = idx % W;
    int t = tb - DIL + j;
    float v = 0.f;
    if (t >= 0 && t < LAUD_) {
      int g = (b*C_ + ci)*LAUD_ + t;
      v = h[g] + ad[g];
    }
    ss[ci][j] = lrelu_(v, 0.2f);
  }
  // zero y2 pads
  if (tb == 0 && threadIdx.x < 128) {
    int ci = threadIdx.x >> 2, q = threadIdx.x & 3;
    y2p[(size_t)(b*C_ + ci)*Y2S + q] = 0.f;
  }
  if (tb == LAUD_ - T && threadIdx.x < 128) {
    int ci = threadIdx.x >> 2, q = threadIdx.x & 3;
    y2p[(size_t)(b*C_ + ci)*Y2S + 4 + LAUD_ + q] = 0.f;
  }
  __syncthreads();
  int co = threadIdx.x & 31, tq = threadIdx.x >> 5;
  float acc[16];
#pragma unroll
  for (int ii = 0; ii < 16; ii++) acc[ii] = 0.f;
  for (int ci = 0; ci < C_; ci++) {
    float w0 = wT[(ci*3 + 0)*32 + co];
    float w1 = wT[(ci*3 + 1)*32 + co];
    float w2 = wT[(ci*3 + 2)*32 + co];
#pragma unroll
    for (int ii = 0; ii < 16; ii++) {
      int tl = tq*16 + ii;
      acc[ii] = fmaf(w0, ss[ci][tl], fmaf(w1, ss[ci][tl + DIL], fmaf(w2, ss[ci][tl + 2*DIL], acc[ii])));
    }
  }
  float* op = y2p + (size_t)(b*C_ + co)*Y2S + 4 + tb + tq*16;
#pragma unroll
  for (int ii = 0; ii < 16; ii++) acc[ii] = lrelu_(acc[ii], 0.2f);
#pragma unroll
  for (int q = 0; q < 4; q++)
    *reinterpret_cast<float4*>(&op[q*4]) = make_float4(acc[q*4], acc[q*4+1], acc[q*4+2], acc[q*4+3]);
}

// ---------------------------------------------------------------- K7: deep-pipelined DMA MFMA KP-GEMM + LVC + gate + h update
// Block = (b, 64 frames, variant v). 8 waves = 4 frame-groups (fg) x 2 gate-halves (tp).
// r13 fixes: (a) sy group-padded SYW layout (36-float slots) -> <=2-way banks (was
// 4-way, 4.27M conflicts); (b) 5-buffer ring, 4 chunks issued ahead / 3 in flight
// after wait (was 1 in flight -> every step ate L2/L3 latency).
// LDS map (147968 B):
//   [0,61440)        stg ring 5 x 12288  (pre-loop: shh [0,16896), FB [17408,41984);
//                     post-loop: red [0,33792))
//   [61440,73728)    kbt_s (96 steps x 2 tp x 16 f32)
//   [73728,147968)   sy (32 ci x 580 f32, SYW-padded)
#define SYW(j) ((((j) >> 5) * 36) + ((j) & 31))

#define STAGE(BUF, STEP)                                                         \
  {                                                                              \
    const unsigned short* gsrc = waf + (size_t)((layer*96 + (STEP))*4)*3072;     \
    { int u = tid; int tpx = (u >= 384); int wi = u - tpx*384;                   \
      GLOAD16(gsrc + (v + 2*tpx)*3072 + wi*8,                                    \
              (char*)stg + (size_t)(BUF)*12288 + u*16); }                        \
    if (tid < 256) { int u = tid + 512; int wi = u - 384;                        \
      GLOAD16(gsrc + (v + 2)*3072 + wi*8,                                        \
              (char*)stg + (size_t)(BUF)*12288 + u*16); }                        \
  }

#define LOADSYR(CI)                                                              \
  float syr[12];                                                                 \
  {                                                                              \
    const float* yrow = sy + (CI)*580;                                           \
    float4 q0 = *reinterpret_cast<const float4*>(yrow + off0);                   \
    float4 q1 = *reinterpret_cast<const float4*>(yrow + off1);                   \
    float4 q2 = *reinterpret_cast<const float4*>(yrow + off2);                   \
    syr[0]=q0.x; syr[1]=q0.y; syr[2]=q0.z; syr[3]=q0.w;                          \
    syr[4]=q1.x; syr[5]=q1.y; syr[6]=q1.z; syr[7]=q1.w;                          \
    syr[8]=q2.x; syr[9]=q2.y; syr[10]=q2.z; syr[11]=q2.w;                        \
  }

#define DOSTEP(CI, KK, ISSUE, WA, WB)                                            \
  {                                                                              \
    const int step_ = (CI)*3 + (KK);                                             \
    const unsigned short* sa = stg + (size_t)(step_ % 5)*6144 + tp*3072;         \
    v4f acc = {0.f, 0.f, 0.f, 0.f};                                              \
    _Pragma("unroll") for (int ks = 0; ks < 6; ks++) {                           \
      v8s a = *reinterpret_cast<const v8s*>(sa + ks*512 + lane*8);               \
      acc = __builtin_amdgcn_mfma_f32_16x16x32_bf16(a, bfr[ks], acc, 0, 0, 0);   \
    }                                                                            \
    float4 kb4 = *reinterpret_cast<const float4*>(&kbt_s[(step_*2 + tp)*16 + kbl]); \
    _Pragma("unroll") for (int r = 0; r < 4; r++) {                              \
      float kern = acc[r] + ((const float*)&kb4)[r];                             \
      _Pragma("unroll") for (int s = 0; s < 8; s++)                              \
        o[r][s] = fmaf(kern, syr[(KK) + s], o[r][s]);                            \
    }                                                                            \
    if ((ISSUE) >= 0) { STAGE(((ISSUE) % 5), (ISSUE)) }                          \
    if (wave < 4) { WAITV(WA); } else { WAITV(WB); }                             \
    __builtin_amdgcn_s_barrier();                                                \
  }

__global__ __launch_bounds__(512, 2) void k_lvc_mfma(
    const float* __restrict__ hkp, const unsigned short* __restrict__ waf,
    const float* __restrict__ kbt, const float* __restrict__ biasb,
    const float* __restrict__ y2p, const float* __restrict__ ad,
    float* __restrict__ h, int layer) {
  int b  = blockIdx.x >> 6;               // grid = B * 32 ftiles * 2 variants = 256
  int r6 = blockIdx.x & 63;
  int l0 = (r6 >> 1) * 64;                // 64 frames per block
  int v  = r6 & 1;

  __shared__ __align__(16) char pool[147968];
  unsigned short* stg   = (unsigned short*)pool;                  // ring, 61440 B
  float*          kbt_s = (float*)(pool + 61440);                 // 12288 B
  float*          sy    = (float*)(pool + 73728);                 // 74240 B
  float*          shh   = (float*)pool;                           // pre-loop alias
  unsigned short* FB    = (unsigned short*)(pool + 17408);        // pre-loop alias
  float*          red   = (float*)pool;                           // post-loop alias

  int tid = threadIdx.x;
  // Phase 1a: sy stage (SYW-padded; y2p padding means t in [-1, LAUD+2] is valid)
  {
    const float* ysrc = y2p + (size_t)(b*C_)*Y2S + 4 + (size_t)l0*8 - 1;
    for (int idx = tid; idx < 32*514; idx += 512) {
      int ci = idx / 514, j = idx % 514;
      sy[ci*580 + SYW(j)] = ysrc[(size_t)ci*Y2S + j];
    }
  }
  // Phase 1b: kbt stage
  for (int u = tid; u < 3072; u += 512) {
    int step = u >> 5, tp2 = (u >> 4) & 1, cr = u & 15;
    kbt_s[u] = kbt[((layer*96 + step)*4 + v + 2*tp2)*16 + cr];
  }
  // Phase 1c: hkp window (frames l0-1 .. l0+64) into shh (aliases ring)
  for (int idx = tid; idx < HID_*66; idx += 512) {
    int hh = idx / 66, j = idx % 66;
    int l = l0 - 1 + j;
    shh[hh*66 + j] = (l >= 0 && l < LMEL_) ? hkp[(b*HID_ + hh)*LMEL_ + l] : 0.f;
  }
  __syncthreads();
  // Phase 2: B fragments for 4 frame-groups (reads shh, writes FB — disjoint)
  for (int u = tid; u < 12288; u += 512) {
    int i = u & 7, lane2 = (u >> 3) & 63, ksf = u >> 9;     // ksf = fg*6 + ks
    int ks = ksf % 6, fg2 = ksf / 6;
    int k = ks*32 + ((lane2 >> 4) << 3) + i;
    int col = lane2 & 15;
    int hh = k / 3, q = k - hh*3;
    FB[u] = f2bf(shh[hh*66 + fg2*16 + col + q]);
  }
  __syncthreads();

  int wave = tid >> 6, lane = tid & 63;
  int tp = wave & 1, fg = wave >> 1;
  int f = lane & 15;
  const int kbl = ((lane >> 4) << 2);

  v8s bfr[6];
#pragma unroll
  for (int ks = 0; ks < 6; ks++)
    bfr[ks] = *reinterpret_cast<const v8s*>(&FB[((fg*6 + ks)*64 + lane)*8]);
  // all waves must finish reading FB before ring DMAs overwrite it
  asm volatile("s_waitcnt lgkmcnt(0)" ::: "memory");
  __syncthreads();

  float o[4][8];
#pragma unroll
  for (int r = 0; r < 4; r++)
#pragma unroll
    for (int s = 0; s < 8; s++) o[r][s] = 0.f;

  // precomputed skewed sy read offsets (bank-spread: <=2-way)
  const int sybase = (fg*16 + f)*8;
  const int off0 = SYW(sybase);
  const int off1 = SYW(sybase + 4);
  const int off2 = SYW(sybase + 8);

  // prologue: chunks 0..3 issued; drain chunk 0 (keep 3 in flight); barrier
  STAGE(0, 0)
  STAGE(1, 1)
  STAGE(2, 2)
  STAGE(3, 3)
  if (wave < 4) { WAITV(6); } else { WAITV(3); }
  __builtin_amdgcn_s_barrier();

  for (int ci = 0; ci < 30; ci++) {
    LOADSYR(ci)
    DOSTEP(ci, 0, ci*3 + 4, 6, 3)
    DOSTEP(ci, 1, ci*3 + 5, 6, 3)
    DOSTEP(ci, 2, ci*3 + 6, 6, 3)
  }
  {
    LOADSYR(30)
    DOSTEP(30, 0, 94, 6, 3)
    DOSTEP(30, 1, 95, 6, 3)
    DOSTEP(30, 2, -1, 4, 2)
  }
  {
    LOADSYR(31)
    DOSTEP(31, 0, -1, 2, 1)
    DOSTEP(31, 1, -1, 0, 0)
    DOSTEP(31, 2, -1, 0, 0)
  }

  // epilogue: bias, gate-pair exchange via red (ring alias, all DMA drained), gate
#pragma unroll
  for (int r = 0; r < 4; r++) {
    int cout = (v + 2*tp)*16 + kbl + r;
    float bv = biasb[((size_t)b*BCH_ + layer*2*C_ + cout)*LMEL_ + l0 + fg*16 + f];
#pragma unroll
    for (int s = 0; s < 8; s++) o[r][s] += bv;
  }
  if (tp == 1) {
#pragma unroll
    for (int r = 0; r < 4; r++)
#pragma unroll
      for (int s = 0; s < 8; s++)
        red[(fg*64 + lane)*33 + r*8 + s] = o[r][s];
  }
  __syncthreads();
  if (tp == 0) {
#pragma unroll
    for (int r = 0; r < 4; r++) {
      int cout = v*16 + kbl + r;
      size_t base = ((size_t)b*C_ + cout)*LAUD_ + (size_t)(l0 + fg*16 + f)*HOP_;
      float4 h0 = *reinterpret_cast<const float4*>(&h[base]);
      float4 h1 = *reinterpret_cast<const float4*>(&h[base + 4]);
      float4 a0 = *reinterpret_cast<const float4*>(&ad[base]);
      float4 a1 = *reinterpret_cast<const float4*>(&ad[base + 4]);
      float outv[8];
#pragma unroll
      for (int s = 0; s < 8; s++) {
        float vv = o[r][s];
        float tv = red[(fg*64 + lane)*33 + r*8 + s];
        float sig = 1.f / (1.f + __expf(-vv));
        float th  = 1.f - 2.f / (1.f + __expf(2.f*tv));
        float hv = (s < 4) ? ((const float*)&h0)[s] : ((const float*)&h1)[s-4];
        float av = (s < 4) ? ((const float*)&a0)[s] : ((const float*)&a1)[s-4];
        outv[s] = hv + av + sig * th;
      }
      *reinterpret_cast<float4*>(&h[base])     = make_float4(outv[0], outv[1], outv[2], outv[3]);
      *reinterpret_cast<float4*>(&h[base + 4]) = make_float4(outv[4], outv[5], outv[6], outv[7]);
    }
  }
}

// ---------------------------------------------------------------- launcher
extern "C" void kernel_launch(void* const* d_in, const int* in_sizes, int n_in,
                              void* d_out, int out_size, void* d_ws, size_t ws_size,
                              hipStream_t stream) {
  const float* x     = (const float*)d_in[0];
  const float* ad    = (const float*)d_in[1];
  const float* c     = (const float*)d_in[2];
  const float* ne    = (const float*)d_in[3];
  const float* fw    = (const float*)d_in[4];
  const float* fb    = (const float*)d_in[5];
  const float* upw   = (const float*)d_in[6];
  const float* convw = (const float*)d_in[7];
  const float* kinw  = (const float*)d_in[8];
  const float* kinb  = (const float*)d_in[9];
  const float* krw1  = (const float*)d_in[10];
  const float* krb1  = (const float*)d_in[11];
  const float* krw2  = (const float*)d_in[12];
  const float* krb2  = (const float*)d_in[13];
  const float* kkw   = (const float*)d_in[14];
  const float* kkb   = (const float*)d_in[15];
  const float* kbw   = (const float*)d_in[16];
  const float* kbb   = (const float*)d_in[17];
  float* h = (float*)d_out;

  float* ws = (float*)d_ws;
  float* cond   = ws; ws += B_*COND_*LMEL_;
  float* hkpa   = ws; ws += B_*HID_*LMEL_;
  float* hkpb   = ws; ws += B_*HID_*LMEL_;
  float* biasb  = ws; ws += B_*BCH_*LMEL_;
  float* y2p    = ws; ws += B_*C_*Y2S;
  float* kbt    = ws; ws += KCH_;
  float* wtup   = ws; ws += C_*C_*16;
  float* kinwT  = ws; ws += HID_*COND_*5;
  float* krw1T  = ws; ws += 3*HID_*HID_*3;
  float* krw2T  = ws; ws += 3*HID_*HID_*3;
  float* kbwT   = ws; ws += BCH_*HID_*3;
  float* convwT = ws; ws += LAYERS_*C_*C_*3;
  unsigned short* waf = (unsigned short*)ws; ws += (KCH_*HID_*KPK_)/2;

  k_mkA<<<(KCH_*HID_*KPK_ + 255)/256, 256, 0, stream>>>(kkw, waf);
  k_mkKbT<<<(KCH_ + 255)/256, 256, 0, stream>>>(kkb, kbt);
  k_mkUp<<<(C_*C_*16 + 255)/256, 256, 0, stream>>>(upw, wtup);
  k_mkWTs<<<(HID_*COND_*5 + 255)/256, 256, 0, stream>>>(kinw, kinwT, 1, HID_, COND_*5);
  k_mkWTs<<<(3*HID_*HID_*3 + 255)/256, 256, 0, stream>>>(krw1, krw1T, 3, HID_, HID_*3);
  k_mkWTs<<<(3*HID_*HID_*3 + 255)/256, 256, 0, stream>>>(krw2, krw2T, 3, HID_, HID_*3);
  k_mkWTs<<<(BCH_*HID_*3 + 255)/256, 256, 0, stream>>>(kbw, kbwT, 1, BCH_, HID_*3);
  k_mkWTs<<<(LAYERS_*C_*C_*3 + 255)/256, 256, 0, stream>>>(convw, convwT, LAYERS_, C_, C_*3);

  k_noise_cond<<<B_*COND_, 256, 0, stream>>>(ne, fw, fb, c, cond);
  k_kp_in<<<B_*(LMEL_/32), 256, 0, stream>>>(cond, kinwT, kinb, hkpa);
  // res chain: a -> b -> a -> b  (final in hkpb)
  k_kp_res2<<<B_*(LMEL_/32), 256, 0, stream>>>(hkpa, krw1T + 0*HID_*HID_*3, krb1 + 0*HID_,
                                               krw2T + 0*HID_*HID_*3, krb2 + 0*HID_, hkpb);
  k_kp_res2<<<B_*(LMEL_/32), 256, 0, stream>>>(hkpb, krw1T + 1*HID_*HID_*3, krb1 + 1*HID_,
                                               krw2T + 1*HID_*HID_*3, krb2 + 1*HID_, hkpa);
  k_kp_res2<<<B_*(LMEL_/32), 256, 0, stream>>>(hkpa, krw1T + 2*HID_*HID_*3, krb1 + 2*HID_,
                                               krw2T + 2*HID_*HID_*3, krb2 + 2*HID_, hkpb);
  k_kp_bias<<<B_*(LMEL_/16), 256, 0, stream>>>(hkpb, kbwT, kbb, biasb);
  k_upsample<<<B_*65, 256, 0, stream>>>(x, wtup, h);

  for (int i = 0; i < LAYERS_; i++) {
    const float* wci = convwT + i*C_*C_*3;
    switch (i) {
      case 0: k_dilconv<1 ><<<B_*(LAUD_/128), 256, 0, stream>>>(h, ad, wci, y2p); break;
      case 1: k_dilconv<3 ><<<B_*(LAUD_/128), 256, 0, stream>>>(h, ad, wci, y2p); break;
      case 2: k_dilconv<9 ><<<B_*(LAUD_/128), 256, 0, stream>>>(h, ad, wci, y2p); break;
      case 3: k_dilconv<27><<<B_*(LAUD_/128), 256, 0, stream>>>(h, ad, wci, y2p); break;
    }
    k_lvc_mfma<<<B_*64, 512, 0, stream>>>(hkpb, waf, kbt, biasb, y2p, ad, h, i);
  }
}

// Round 15
// 460.038 us; speedup vs baseline: 1.5062x; 1.0638x over previous
//
#include <hip/hip_runtime.h>
#include <math.h>

#define B_      4
#define C_      32
#define COND_   80
#define LMEL_   2048
#define HOP_    8
#define UP_     8
#define LAYERS_ 4
#define K_      3
#define HID_    64
#define KPK_    3
#define EMB_    512
#define LAUD_   (LMEL_*UP_)          // 16384
#define KCH_    (LAYERS_*C_*2*C_*K_) // 24576
#define BCH_    (LAYERS_*2*C_)       // 256
#define Y2S     (LAUD_ + 8)          // padded y2 row stride (+4 each side)

typedef short v8s __attribute__((ext_vector_type(8)));
typedef float v4f __attribute__((ext_vector_type(4)));

__device__ __forceinline__ float lrelu_(float v, float s) { return v >= 0.f ? v : s * v; }

__device__ __forceinline__ unsigned short f2bf(float f) {  // RNE float->bf16
  unsigned int x = __float_as_uint(f);
  unsigned int r = (x + 0x7FFFu + ((x >> 16) & 1u)) >> 16;
  return (unsigned short)r;
}

// async global->LDS DMA, 16B per lane (guide §5: dest = wave-uniform base + lane*16)
#define GLOAD16(GSRC, LDST)                                              \
  __builtin_amdgcn_global_load_lds(                                     \
      (const __attribute__((address_space(1))) unsigned int*)(GSRC),    \
      (__attribute__((address_space(3))) unsigned int*)(LDST), 16, 0, 0)

#define WAITV(N) asm volatile("s_waitcnt vmcnt(" #N ")" ::: "memory")

// ---------------------------------------------------------------- prep: generic slab transpose src[s][oc][ick] -> dst[s][ick][oc]
__global__ void k_mkWTs(const float* __restrict__ src, float* __restrict__ dst,
                        int S, int OC, int ICK) {
  int idx = blockIdx.x*256 + threadIdx.x;
  if (idx >= S*OC*ICK) return;
  int s = idx / (OC*ICK), rem = idx % (OC*ICK);
  int oc = rem / ICK, ick = rem % ICK;
  dst[s*OC*ICK + ick*OC + oc] = src[idx];
}

// ---------------------------------------------------------------- K1: noise + condition
__global__ void k_noise_cond(const float* __restrict__ ne, const float* __restrict__ fw,
                             const float* __restrict__ fb, const float* __restrict__ c,
                             float* __restrict__ cond) {
  int b = blockIdx.x / COND_;
  int cc = blockIdx.x % COND_;
  __shared__ float red[256];
  float p = 0.f;
  for (int j = threadIdx.x; j < EMB_; j += 256)
    p += ne[b*EMB_ + j] * fw[cc*EMB_ + j];
  red[threadIdx.x] = p;
  __syncthreads();
  for (int s = 128; s > 0; s >>= 1) {
    if (threadIdx.x < s) red[threadIdx.x] += red[threadIdx.x + s];
    __syncthreads();
  }
  float noise = red[0] + fb[cc];
  const float* cp = c + (b*COND_ + cc)*LMEL_;
  float* op = cond + (b*COND_ + cc)*LMEL_;
  for (int l = threadIdx.x; l < LMEL_; l += 256) op[l] = cp[l] + noise;
}

// ---------------------------------------------------------------- K2: KP input conv (80->64, k=5, pad=2, lrelu 0.1), T=32, wT[(cc*5+k)*64+ch]
__global__ __launch_bounds__(256) void k_kp_in(const float* __restrict__ cond, const float* __restrict__ wT,
                                               const float* __restrict__ bias, float* __restrict__ out) {
  const int T = 32;
  int b  = blockIdx.x / (LMEL_/T);
  int lb = (blockIdx.x % (LMEL_/T)) * T;
  __shared__ float sc[COND_][T + 4];
  for (int idx = threadIdx.x; idx < COND_*(T+4); idx += 256) {
    int cc = idx / (T+4), j = idx % (T+4);
    int l = lb + j - 2;
    sc[cc][j] = (l >= 0 && l < LMEL_) ? cond[(b*COND_ + cc)*LMEL_ + l] : 0.f;
  }
  __syncthreads();
  int ch = threadIdx.x & 63;
  int lq = threadIdx.x >> 6;  // 0..3, 8 l's each
  float acc[8];
#pragma unroll
  for (int ii = 0; ii < 8; ii++) acc[ii] = bias[ch];
  for (int cc = 0; cc < COND_; cc++) {
    float r[12];
#pragma unroll
    for (int j = 0; j < 12; j++) r[j] = sc[cc][lq*8 + j];
#pragma unroll
    for (int k = 0; k < 5; k++) {
      float wv = wT[(cc*5 + k)*64 + ch];
#pragma unroll
      for (int ii = 0; ii < 8; ii++) acc[ii] = fmaf(wv, r[ii + k], acc[ii]);
    }
  }
  float* op = out + (b*HID_ + ch)*LMEL_ + lb + lq*8;
#pragma unroll
  for (int ii = 0; ii < 8; ii++) acc[ii] = lrelu_(acc[ii], 0.1f);
  *reinterpret_cast<float4*>(&op[0]) = make_float4(acc[0], acc[1], acc[2], acc[3]);
  *reinterpret_cast<float4*>(&op[4]) = make_float4(acc[4], acc[5], acc[6], acc[7]);
}

// ---------------------------------------------------------------- K3: fused res pair: out = in + lrelu(conv2(lrelu(conv1(in))))
__global__ __launch_bounds__(256) void k_kp_res2(const float* __restrict__ in,
                                                 const float* __restrict__ w1T, const float* __restrict__ b1,
                                                 const float* __restrict__ w2T, const float* __restrict__ b2,
                                                 float* __restrict__ out) {
  const int T = 32;
  int b  = blockIdx.x / (LMEL_/T);
  int lb = (blockIdx.x % (LMEL_/T)) * T;
  __shared__ float si[HID_][38];   // cols lb-2 .. lb+33 (36 used)
  __shared__ float sr[HID_][38];   // intermediate r, cols lb-1 .. lb+32 (34 used)
  for (int idx = threadIdx.x; idx < HID_*36; idx += 256) {
    int cc = idx / 36, j = idx % 36;
    int l = lb - 2 + j;
    si[cc][j] = (l >= 0 && l < LMEL_) ? in[(b*HID_ + cc)*LMEL_ + l] : 0.f;
  }
  __syncthreads();
  int ch = threadIdx.x & 63;
  int lq = threadIdx.x >> 6;   // 0..3
  {
    float b1v = b1[ch];
    float a1[9];
#pragma unroll
    for (int jj = 0; jj < 9; jj++) a1[jj] = b1v;
    for (int cc = 0; cc < HID_; cc++) {
      float r[11];
#pragma unroll
      for (int j = 0; j < 11; j++) r[j] = si[cc][lq*9 + j];
#pragma unroll
      for (int k = 0; k < 3; k++) {
        float wv = w1T[(cc*3 + k)*64 + ch];
#pragma unroll
        for (int jj = 0; jj < 9; jj++) a1[jj] = fmaf(wv, r[jj + k], a1[jj]);
      }
    }
#pragma unroll
    for (int jj = 0; jj < 9; jj++) {
      int m = lq*9 + jj;
      if (m < 34) sr[ch][m] = lrelu_(a1[jj], 0.1f);
    }
  }
  __syncthreads();
  {
    float b2v = b2[ch];
    float a2[8];
#pragma unroll
    for (int jj = 0; jj < 8; jj++) a2[jj] = b2v;
    for (int cc = 0; cc < HID_; cc++) {
      float r[10];
#pragma unroll
      for (int j = 0; j < 10; j++) r[j] = sr[cc][lq*8 + j];
#pragma unroll
      for (int k = 0; k < 3; k++) {
        float wv = w2T[(cc*3 + k)*64 + ch];
#pragma unroll
        for (int jj = 0; jj < 8; jj++) a2[jj] = fmaf(wv, r[jj + k], a2[jj]);
      }
    }
    float* op = out + (b*HID_ + ch)*LMEL_ + lb + lq*8;
    float v[8];
#pragma unroll
    for (int jj = 0; jj < 8; jj++)
      v[jj] = si[ch][lq*8 + jj + 2] + lrelu_(a2[jj], 0.1f);
    *reinterpret_cast<float4*>(&op[0]) = make_float4(v[0], v[1], v[2], v[3]);
    *reinterpret_cast<float4*>(&op[4]) = make_float4(v[4], v[5], v[6], v[7]);
  }
}

// ---------------------------------------------------------------- K4: bias conv (64->256, k=3, pad=1), T=16, wT[(cc*3+k)*256+ch]
__global__ __launch_bounds__(256) void k_kp_bias(const float* __restrict__ in, const float* __restrict__ wT,
                                                 const float* __restrict__ bias, float* __restrict__ out) {
  const int T = 16;
  int b  = blockIdx.x / (LMEL_/T);
  int lb = (blockIdx.x % (LMEL_/T)) * T;
  __shared__ float si[HID_][T + 2];
  for (int idx = threadIdx.x; idx < HID_*(T+2); idx += 256) {
    int cc = idx / (T+2), j = idx % (T+2);
    int l = lb + j - 1;
    si[cc][j] = (l >= 0 && l < LMEL_) ? in[(b*HID_ + cc)*LMEL_ + l] : 0.f;
  }
  __syncthreads();
  int ch = threadIdx.x;  // 0..255
  float acc[T];
  float bv = bias[ch];
#pragma unroll
  for (int ii = 0; ii < T; ii++) acc[ii] = bv;
  for (int cc = 0; cc < HID_; cc++) {
    float w0 = wT[(cc*3 + 0)*256 + ch];
    float w1 = wT[(cc*3 + 1)*256 + ch];
    float w2 = wT[(cc*3 + 2)*256 + ch];
#pragma unroll
    for (int ii = 0; ii < T; ii++)
      acc[ii] = fmaf(w0, si[cc][ii], fmaf(w1, si[cc][ii+1], fmaf(w2, si[cc][ii+2], acc[ii])));
  }
  float* op = out + (b*BCH_ + ch)*LMEL_ + lb;
#pragma unroll
  for (int q = 0; q < 4; q++)
    *reinterpret_cast<float4*>(&op[q*4]) = make_float4(acc[q*4], acc[q*4+1], acc[q*4+2], acc[q*4+3]);
}

// ---------------------------------------------------------------- prep: upsample weight transpose -> wt[(ci*16+j)*32+co]
__global__ void k_mkUp(const float* __restrict__ upw, float* __restrict__ wt) {
  int idx = blockIdx.x*256 + threadIdx.x;
  if (idx >= C_*C_*16) return;
  int co = idx & 31, j = (idx >> 5) & 15, ci = idx >> 9;
  wt[idx] = upw[(ci*C_ + co)*16 + j];
}

// ---------------------------------------------------------------- K5: upsample (conv_transpose1d stride 8, k=16, pad=4), lrelu(x,0.2) input
#define UT 32
__global__ __launch_bounds__(256) void k_upsample(const float* __restrict__ x, const float* __restrict__ wt,
                                                  float* __restrict__ h) {
  int b  = blockIdx.x / 65;
  int s0 = (blockIdx.x % 65) * UT;
  __shared__ float sw[16384];          // [ci][j][co]
  __shared__ float sx[C_][33 + 3];
  for (int idx = threadIdx.x*4; idx < 16384; idx += 1024)
    *reinterpret_cast<float4*>(&sw[idx]) = *reinterpret_cast<const float4*>(&wt[idx]);
  for (int idx = threadIdx.x; idx < C_*33; idx += 256) {
    int ci = idx / 33, i = idx % 33;
    int s = s0 - 1 + i;
    float v = (s >= 0 && s < LMEL_) ? x[(b*C_ + ci)*LMEL_ + s] : 0.f;
    sx[ci][i] = lrelu_(v, 0.2f);
  }
  __syncthreads();
  int co = threadIdx.x & 31, sq = threadIdx.x >> 5;  // sq 0..7, 4 frames each
  float acc[4][8];
#pragma unroll
  for (int k = 0; k < 4; k++)
#pragma unroll
    for (int r = 0; r < 8; r++) acc[k][r] = 0.f;
  for (int ci = 0; ci < C_; ci++) {
    float xv[5];
#pragma unroll
    for (int m = 0; m < 5; m++) xv[m] = sx[ci][sq*4 + m];
    const float* wl = &sw[ci*512 + co];
#pragma unroll
    for (int r = 0; r < 8; r++) {
      float wa = wl[r*32];
      float wb = wl[(r+8)*32];
#pragma unroll
      for (int k = 0; k < 4; k++)
        acc[k][r] = fmaf(wa, xv[k+1], fmaf(wb, xv[k], acc[k][r]));
    }
  }
  float* op = h + ((size_t)b*C_ + co)*LAUD_;
#pragma unroll
  for (int k = 0; k < 4; k++) {
    int s1 = s0 + sq*4 + k;
    int lo = 8*s1 - 4;
    if (lo >= 0 && lo + 4 <= LAUD_)
      *reinterpret_cast<float4*>(&op[lo]) = make_float4(acc[k][0], acc[k][1], acc[k][2], acc[k][3]);
    if (lo >= -4 && lo + 8 <= LAUD_)
      *reinterpret_cast<float4*>(&op[lo+4]) = make_float4(acc[k][4], acc[k][5], acc[k][6], acc[k][7]);
  }
}

// ---------------------------------------------------------------- prep: A-fragment-ordered bf16 weights
__global__ void k_mkA(const float* __restrict__ kw, unsigned short* __restrict__ waf) {
  int idx = blockIdx.x*256 + threadIdx.x;
  if (idx >= KCH_*HID_*KPK_) return;   // 4,718,592
  int i    = idx & 7;
  int lane = (idx >> 3) & 63;
  int ks   = (idx >> 9) % 6;
  int tile = (idx / 3072) & 3;
  int rk   = idx / 12288;              // 0..383
  int layer = rk / 96, rem = rk % 96, ci = rem / 3, kk = rem % 3;
  int cout = tile*16 + (lane & 15);
  int j    = ks*32 + ((lane >> 4) << 3) + i;
  int row  = ((layer*32 + ci)*64 + cout)*3 + kk;
  waf[idx] = f2bf(kw[row*192 + j]);
}

// ---------------------------------------------------------------- prep: kernel-conv bias reordered
__global__ void k_mkKbT(const float* __restrict__ kb, float* __restrict__ kbt) {
  int idx = blockIdx.x*256 + threadIdx.x;
  if (idx >= KCH_) return;             // 24576
  int cr = idx & 15, tile = (idx >> 4) & 3, rk = idx >> 6;
  int layer = rk / 96, rem = rk % 96, ci = rem / 3, kk = rem % 3;
  int cout = tile*16 + cr;
  kbt[idx] = kb[((layer*32 + ci)*64 + cout)*3 + kk];
}

// ---------------------------------------------------------------- K6: dilated conv (32->32, k=3) on lrelu(h+ad,0.2), out lrelu 0.2, T=128
template<int DIL>
__global__ __launch_bounds__(256) void k_dilconv(const float* __restrict__ h, const float* __restrict__ ad,
                                                 const float* __restrict__ wT, float* __restrict__ y2p) {
  const int T = 128;
  int b  = blockIdx.x / (LAUD_/T);
  int tb = (blockIdx.x % (LAUD_/T)) * T;
  const int W = T + 2*DIL;
  __shared__ float ss[C_][T + 2*27 + 4];
  for (int idx = threadIdx.x; idx < C_*W; idx += 256) {
    int ci = idx / W, j = idx % W;
    int t = tb - DIL + j;
    float v = 0.f;
    if (t >= 0 && t < LAUD_) {
      int g = (b*C_ + ci)*LAUD_ + t;
      v = h[g] + ad[g];
    }
    ss[ci][j] = lrelu_(v, 0.2f);
  }
  // zero y2 pads
  if (tb == 0 && threadIdx.x < 128) {
    int ci = threadIdx.x >> 2, q = threadIdx.x & 3;
    y2p[(size_t)(b*C_ + ci)*Y2S + q] = 0.f;
  }
  if (tb == LAUD_ - T && threadIdx.x < 128) {
    int ci = threadIdx.x >> 2, q = threadIdx.x & 3;
    y2p[(size_t)(b*C_ + ci)*Y2S + 4 + LAUD_ + q] = 0.f;
  }
  __syncthreads();
  int co = threadIdx.x & 31, tq = threadIdx.x >> 5;
  float acc[16];
#pragma unroll
  for (int ii = 0; ii < 16; ii++) acc[ii] = 0.f;
  for (int ci = 0; ci < C_; ci++) {
    float w0 = wT[(ci*3 + 0)*32 + co];
    float w1 = wT[(ci*3 + 1)*32 + co];
    float w2 = wT[(ci*3 + 2)*32 + co];
#pragma unroll
    for (int ii = 0; ii < 16; ii++) {
      int tl = tq*16 + ii;
      acc[ii] = fmaf(w0, ss[ci][tl], fmaf(w1, ss[ci][tl + DIL], fmaf(w2, ss[ci][tl + 2*DIL], acc[ii])));
    }
  }
  float* op = y2p + (size_t)(b*C_ + co)*Y2S + 4 + tb + tq*16;
#pragma unroll
  for (int ii = 0; ii < 16; ii++) acc[ii] = lrelu_(acc[ii], 0.2f);
#pragma unroll
  for (int q = 0; q < 4; q++)
    *reinterpret_cast<float4*>(&op[q*4]) = make_float4(acc[q*4], acc[q*4+1], acc[q*4+2], acc[q*4+3]);
}

// ---------------------------------------------------------------- K7: fg-paired DMA-pipelined MFMA KP-GEMM + LVC + gate + h update
// Block = (b, 64 frames, variant v). 8 waves = fg{0,1: 32 frames, 2 B-sets} x tp{gate
// half} x ch{ci-half}. Each wave: 12 MFMA per 6 A-reads (2x LDS-read reuse vs r14),
// 48 phases (vs 96 barriers). Phase p: ch0 computes step p, ch1 step 48+p; STAGE2
// stages both chunks (24KB = exactly 3 GLOAD16/thread, uniform vmcnt). 3-deep ring.
// Epilogue: ch-reduction + gate exchange, once.
// LDS map (160256 B):
//   [0,73728)        ring 3 x 24576 (pre-loop: shh [0,16896), FB [16896,41472);
//                     post-loop: red [0,66560))
//   [73728,147968)   sy (32 ci x 580 f32, SYW-padded)
//   [147968,160256)  kbt_s (96 steps x 2 tp x 16 f32)
#define SYW(j) ((((j) >> 5) * 36) + ((j) & 31))

#define STAGE2(PH)                                                               \
  {                                                                              \
    const size_t rbase = (size_t)(layer*96 + (PH))*4*3072;                       \
    const size_t rbase2 = (size_t)(layer*96 + 48 + (PH))*4*3072;                 \
    char* dst = (char*)stg + (size_t)((PH) % 3)*24576;                           \
    _Pragma("unroll") for (int kq = 0; kq < 3; kq++) {                           \
      int u = tid + kq*512;                                                      \
      int seg = u / 384, wi = u - seg*384;                                       \
      size_t src = (seg < 2 ? rbase : rbase2) + (size_t)(v + 2*(seg & 1))*3072;  \
      GLOAD16(waf + src + wi*8, dst + u*16);                                     \
    }                                                                            \
  }

#define LOADSYR2()                                                               \
  {                                                                              \
    const float* yrow = sy + ciw*580;                                            \
    float4 a0 = *reinterpret_cast<const float4*>(yrow + off00);                  \
    float4 a1 = *reinterpret_cast<const float4*>(yrow + off01);                  \
    float4 a2 = *reinterpret_cast<const float4*>(yrow + off02);                  \
    syr0[0]=a0.x; syr0[1]=a0.y; syr0[2]=a0.z; syr0[3]=a0.w;                      \
    syr0[4]=a1.x; syr0[5]=a1.y; syr0[6]=a1.z; syr0[7]=a1.w;                      \
    syr0[8]=a2.x; syr0[9]=a2.y; syr0[10]=a2.z; syr0[11]=a2.w;                    \
    float4 b0 = *reinterpret_cast<const float4*>(yrow + off10);                  \
    float4 b1 = *reinterpret_cast<const float4*>(yrow + off11);                  \
    float4 b2 = *reinterpret_cast<const float4*>(yrow + off12);                  \
    syr1[0]=b0.x; syr1[1]=b0.y; syr1[2]=b0.z; syr1[3]=b0.w;                      \
    syr1[4]=b1.x; syr1[5]=b1.y; syr1[6]=b1.z; syr1[7]=b1.w;                      \
    syr1[8]=b2.x; syr1[9]=b2.y; syr1[10]=b2.z; syr1[11]=b2.w;                    \
  }

// compute phase (cw*3+KK); ISSUE_OK: stage phase+2; WN: post-issue vmcnt target
#define DOSTEP2(KK, ISSUE_OK, WN)                                                \
  {                                                                              \
    const unsigned short* sa = stg + (size_t)(KK)*12288 + ch*6144 + tp*3072;     \
    v4f acc0 = {0.f,0.f,0.f,0.f}, acc1 = {0.f,0.f,0.f,0.f};                      \
    _Pragma("unroll") for (int ks = 0; ks < 6; ks++) {                           \
      v8s a = *reinterpret_cast<const v8s*>(sa + ks*512 + lane*8);               \
      acc0 = __builtin_amdgcn_mfma_f32_16x16x32_bf16(a, bfrA[ks], acc0, 0, 0, 0);\
      acc1 = __builtin_amdgcn_mfma_f32_16x16x32_bf16(a, bfrB[ks], acc1, 0, 0, 0);\
    }                                                                            \
    int step_ = ch*48 + cw*3 + (KK);                                             \
    float4 kb4 = *reinterpret_cast<const float4*>(&kbt_s[(step_*2 + tp)*16 + kbl]); \
    _Pragma("unroll") for (int r = 0; r < 4; r++) {                              \
      float k0 = acc0[r] + ((const float*)&kb4)[r];                              \
      float k1 = acc1[r] + ((const float*)&kb4)[r];                              \
      _Pragma("unroll") for (int s = 0; s < 8; s++) {                            \
        o0[r][s] = fmaf(k0, syr0[(KK) + s], o0[r][s]);                           \
        o1[r][s] = fmaf(k1, syr1[(KK) + s], o1[r][s]);                           \
      }                                                                          \
    }                                                                            \
    if (ISSUE_OK) { STAGE2(cw*3 + (KK) + 2) }                                    \
    WAITV(WN);                                                                   \
    __builtin_amdgcn_s_barrier();                                                \
  }

__global__ __launch_bounds__(512, 2) void k_lvc_mfma(
    const float* __restrict__ hkp, const unsigned short* __restrict__ waf,
    const float* __restrict__ kbt, const float* __restrict__ biasb,
    const float* __restrict__ y2p, const float* __restrict__ ad,
    float* __restrict__ h, int layer) {
  int b  = blockIdx.x >> 6;               // grid = B * 32 ftiles * 2 variants = 256
  int r6 = blockIdx.x & 63;
  int l0 = (r6 >> 1) * 64;                // 64 frames per block
  int v  = r6 & 1;

  __shared__ __align__(16) char pool[160256];
  unsigned short* stg   = (unsigned short*)pool;                  // ring, 73728 B
  float*          sy    = (float*)(pool + 73728);                 // 74240 B
  float*          kbt_s = (float*)(pool + 147968);                // 12288 B
  float*          shh   = (float*)pool;                           // pre-loop alias
  unsigned short* FB    = (unsigned short*)(pool + 16896);        // pre-loop alias
  float*          red   = (float*)pool;                           // post-loop alias

  int tid = threadIdx.x;
  // Phase 1a: sy stage (SYW-padded; y2p padding makes t in [-1, LAUD+2] valid)
  {
    const float* ysrc = y2p + (size_t)(b*C_)*Y2S + 4 + (size_t)l0*8 - 1;
    for (int idx = tid; idx < 32*514; idx += 512) {
      int ci = idx / 514, j = idx % 514;
      sy[ci*580 + SYW(j)] = ysrc[(size_t)ci*Y2S + j];
    }
  }
  // Phase 1b: kbt stage
  for (int u = tid; u < 3072; u += 512) {
    int step = u >> 5, tp2 = (u >> 4) & 1, cr = u & 15;
    kbt_s[u] = kbt[((layer*96 + step)*4 + v + 2*tp2)*16 + cr];
  }
  // Phase 1c: hkp window (frames l0-1 .. l0+64) into shh (aliases ring)
  for (int idx = tid; idx < HID_*66; idx += 512) {
    int hh = idx / 66, j = idx % 66;
    int l = l0 - 1 + j;
    shh[hh*66 + j] = (l >= 0 && l < LMEL_) ? hkp[(b*HID_ + hh)*LMEL_ + l] : 0.f;
  }
  __syncthreads();
  // Phase 2: B fragments for 4 16-frame groups (reads shh, writes FB — disjoint)
  for (int u = tid; u < 12288; u += 512) {
    int i = u & 7, lane2 = (u >> 3) & 63, ksf = u >> 9;     // ksf = g2*6 + ks
    int ks = ksf % 6, g2 = ksf / 6;
    int k = ks*32 + ((lane2 >> 4) << 3) + i;
    int col = lane2 & 15;
    int hh = k / 3, q = k - hh*3;
    FB[u] = f2bf(shh[hh*66 + g2*16 + col + q]);
  }
  __syncthreads();

  int wave = tid >> 6, lane = tid & 63;
  int tp = wave & 1, ch = (wave >> 1) & 1, fg = wave >> 2;  // fg 0..1
  int f = lane & 15;
  const int kbl = ((lane >> 4) << 2);

  v8s bfrA[6], bfrB[6];
#pragma unroll
  for (int ks = 0; ks < 6; ks++) {
    bfrA[ks] = *reinterpret_cast<const v8s*>(&FB[(((2*fg)*6 + ks)*64 + lane)*8]);
    bfrB[ks] = *reinterpret_cast<const v8s*>(&FB[(((2*fg + 1)*6 + ks)*64 + lane)*8]);
  }
  // all waves must finish reading FB before ring DMAs overwrite it
  asm volatile("s_waitcnt lgkmcnt(0)" ::: "memory");
  __syncthreads();

  float o0[4][8], o1[4][8];
#pragma unroll
  for (int r = 0; r < 4; r++)
#pragma unroll
    for (int s = 0; s < 8; s++) { o0[r][s] = 0.f; o1[r][s] = 0.f; }

  // skewed sy read offsets for the two 16-frame sets of this fg
  const int sb0 = (fg*32 + f)*8, sb1 = (fg*32 + 16 + f)*8;
  const int off00 = SYW(sb0), off01 = SYW(sb0+4), off02 = SYW(sb0+8);
  const int off10 = SYW(sb1), off11 = SYW(sb1+4), off12 = SYW(sb1+8);

  // prologue: phases 0,1 staged (6 DMA/thread); wait phase0 (keep 3 in flight)
  STAGE2(0)
  STAGE2(1)
  WAITV(3);
  __builtin_amdgcn_s_barrier();

  float syr0[12], syr1[12];
  for (int cw = 0; cw < 15; cw++) {
    const int ciw = ch*16 + cw;
    LOADSYR2()
    DOSTEP2(0, 1, 3)
    DOSTEP2(1, 1, 3)
    DOSTEP2(2, 1, 3)
  }
  {
    const int cw = 15;
    const int ciw = ch*16 + 15;
    LOADSYR2()
    DOSTEP2(0, 1, 3)     // issues phase 47
    DOSTEP2(1, 0, 0)     // drain phase 47
    DOSTEP2(2, 0, 0)
  }

  // ---- epilogue: ch-reduce, bias, gate exchange, h update ----
  // red[(fg*2+tp)][lane][g*32+r*8+s], stride 65 (conflict-free)
#define REDI(FGTP, L, IDX) red[((FGTP)*64 + (L))*65 + (IDX)]
  if (ch == 1) {
#pragma unroll
    for (int r = 0; r < 4; r++)
#pragma unroll
      for (int s = 0; s < 8; s++) {
        REDI(fg*2 + tp, lane, r*8 + s)      = o0[r][s];
        REDI(fg*2 + tp, lane, 32 + r*8 + s) = o1[r][s];
      }
  }
  __syncthreads();
  if (ch == 0) {
    int cout = (v + 2*tp)*16 + kbl;
#pragma unroll
    for (int r = 0; r < 4; r++) {
      float bv0 = biasb[((size_t)b*BCH_ + layer*2*C_ + cout + r)*LMEL_ + l0 + fg*32 + f];
      float bv1 = biasb[((size_t)b*BCH_ + layer*2*C_ + cout + r)*LMEL_ + l0 + fg*32 + 16 + f];
#pragma unroll
      for (int s = 0; s < 8; s++) {
        o0[r][s] += REDI(fg*2 + tp, lane, r*8 + s) + bv0;
        o1[r][s] += REDI(fg*2 + tp, lane, 32 + r*8 + s) + bv1;
      }
    }
  }
  __syncthreads();
  if (ch == 0 && tp == 1) {
#pragma unroll
    for (int r = 0; r < 4; r++)
#pragma unroll
      for (int s = 0; s < 8; s++) {
        REDI(fg*2 + 1, lane, r*8 + s)      = o0[r][s];
        REDI(fg*2 + 1, lane, 32 + r*8 + s) = o1[r][s];
      }
  }
  __syncthreads();
  if (ch == 0 && tp == 0) {
#pragma unroll
    for (int g = 0; g < 2; g++) {
#pragma unroll
      for (int r = 0; r < 4; r++) {
        int cout = v*16 + kbl + r;
        size_t base = ((size_t)b*C_ + cout)*LAUD_ + (size_t)(l0 + fg*32 + g*16 + f)*HOP_;
        float4 h0 = *reinterpret_cast<const float4*>(&h[base]);
        float4 h1 = *reinterpret_cast<const float4*>(&h[base + 4]);
        float4 a0 = *reinterpret_cast<const float4*>(&ad[base]);
        float4 a1 = *reinterpret_cast<const float4*>(&ad[base + 4]);
        float outv[8];
#pragma unroll
        for (int s = 0; s < 8; s++) {
          float vv = g ? o1[r][s] : o0[r][s];
          float tv = REDI(fg*2 + 1, lane, g*32 + r*8 + s);
          float sig = 1.f / (1.f + __expf(-vv));
          float th  = 1.f - 2.f / (1.f + __expf(2.f*tv));
          float hv = (s < 4) ? ((const float*)&h0)[s] : ((const float*)&h1)[s-4];
          float av = (s < 4) ? ((const float*)&a0)[s] : ((const float*)&a1)[s-4];
          outv[s] = hv + av + sig * th;
        }
        *reinterpret_cast<float4*>(&h[base])     = make_float4(outv[0], outv[1], outv[2], outv[3]);
        *reinterpret_cast<float4*>(&h[base + 4]) = make_float4(outv[4], outv[5], outv[6], outv[7]);
      }
    }
  }
}

// ---------------------------------------------------------------- launcher
extern "C" void kernel_launch(void* const* d_in, const int* in_sizes, int n_in,
                              void* d_out, int out_size, void* d_ws, size_t ws_size,
                              hipStream_t stream) {
  const float* x     = (const float*)d_in[0];
  const float* ad    = (const float*)d_in[1];
  const float* c     = (const float*)d_in[2];
  const float* ne    = (const float*)d_in[3];
  const float* fw    = (const float*)d_in[4];
  const float* fb    = (const float*)d_in[5];
  const float* upw   = (const float*)d_in[6];
  const float* convw = (const float*)d_in[7];
  const float* kinw  = (const float*)d_in[8];
  const float* kinb  = (const float*)d_in[9];
  const float* krw1  = (const float*)d_in[10];
  const float* krb1  = (const float*)d_in[11];
  const float* krw2  = (const float*)d_in[12];
  const float* krb2  = (const float*)d_in[13];
  const float* kkw   = (const float*)d_in[14];
  const float* kkb   = (const float*)d_in[15];
  const float* kbw   = (const float*)d_in[16];
  const float* kbb   = (const float*)d_in[17];
  float* h = (float*)d_out;

  float* ws = (float*)d_ws;
  float* cond   = ws; ws += B_*COND_*LMEL_;
  float* hkpa   = ws; ws += B_*HID_*LMEL_;
  float* hkpb   = ws; ws += B_*HID_*LMEL_;
  float* biasb  = ws; ws += B_*BCH_*LMEL_;
  float* y2p    = ws; ws += B_*C_*Y2S;
  float* kbt    = ws; ws += KCH_;
  float* wtup   = ws; ws += C_*C_*16;
  float* kinwT  = ws; ws += HID_*COND_*5;
  float* krw1T  = ws; ws += 3*HID_*HID_*3;
  float* krw2T  = ws; ws += 3*HID_*HID_*3;
  float* kbwT   = ws; ws += BCH_*HID_*3;
  float* convwT = ws; ws += LAYERS_*C_*C_*3;
  unsigned short* waf = (unsigned short*)ws; ws += (KCH_*HID_*KPK_)/2;

  k_mkA<<<(KCH_*HID_*KPK_ + 255)/256, 256, 0, stream>>>(kkw, waf);
  k_mkKbT<<<(KCH_ + 255)/256, 256, 0, stream>>>(kkb, kbt);
  k_mkUp<<<(C_*C_*16 + 255)/256, 256, 0, stream>>>(upw, wtup);
  k_mkWTs<<<(HID_*COND_*5 + 255)/256, 256, 0, stream>>>(kinw, kinwT, 1, HID_, COND_*5);
  k_mkWTs<<<(3*HID_*HID_*3 + 255)/256, 256, 0, stream>>>(krw1, krw1T, 3, HID_, HID_*3);
  k_mkWTs<<<(3*HID_*HID_*3 + 255)/256, 256, 0, stream>>>(krw2, krw2T, 3, HID_, HID_*3);
  k_mkWTs<<<(BCH_*HID_*3 + 255)/256, 256, 0, stream>>>(kbw, kbwT, 1, BCH_, HID_*3);
  k_mkWTs<<<(LAYERS_*C_*C_*3 + 255)/256, 256, 0, stream>>>(convw, convwT, LAYERS_, C_, C_*3);

  k_noise_cond<<<B_*COND_, 256, 0, stream>>>(ne, fw, fb, c, cond);
  k_kp_in<<<B_*(LMEL_/32), 256, 0, stream>>>(cond, kinwT, kinb, hkpa);
  // res chain: a -> b -> a -> b  (final in hkpb)
  k_kp_res2<<<B_*(LMEL_/32), 256, 0, stream>>>(hkpa, krw1T + 0*HID_*HID_*3, krb1 + 0*HID_,
                                               krw2T + 0*HID_*HID_*3, krb2 + 0*HID_, hkpb);
  k_kp_res2<<<B_*(LMEL_/32), 256, 0, stream>>>(hkpb, krw1T + 1*HID_*HID_*3, krb1 + 1*HID_,
                                               krw2T + 1*HID_*HID_*3, krb2 + 1*HID_, hkpa);
  k_kp_res2<<<B_*(LMEL_/32), 256, 0, stream>>>(hkpa, krw1T + 2*HID_*HID_*3, krb1 + 2*HID_,
                                               krw2T + 2*HID_*HID_*3, krb2 + 2*HID_, hkpb);
  k_kp_bias<<<B_*(LMEL_/16), 256, 0, stream>>>(hkpb, kbwT, kbb, biasb);
  k_upsample<<<B_*65, 256, 0, stream>>>(x, wtup, h);

  for (int i = 0; i < LAYERS_; i++) {
    const float* wci = convwT + i*C_*C_*3;
    switch (i) {
      case 0: k_dilconv<1 ><<<B_*(LAUD_/128), 256, 0, stream>>>(h, ad, wci, y2p); break;
      case 1: k_dilconv<3 ><<<B_*(LAUD_/128), 256, 0, stream>>>(h, ad, wci, y2p); break;
      case 2: k_dilconv<9 ><<<B_*(LAUD_/128), 256, 0, stream>>>(h, ad, wci, y2p); break;
      case 3: k_dilconv<27><<<B_*(LAUD_/128), 256, 0, stream>>>(h, ad, wci, y2p); break;
    }
    k_lvc_mfma<<<B_*64, 512, 0, stream>>>(hkpb, waf, kbt, biasb, y2p, ad, h, i);
  }
}